// Round 6
// baseline (13632.524 us; speedup 1.0000x reference)
//
#include <hip/hip_runtime.h>

#define NV 50257
#define BOSTOK 50256
#define LNEPS 1e-5f
#define NSTEP 49
#define NBLK 256
#define RPB 197          // fc rows per block: 256*197 = 50432 >= 50257
#define DYN_LDS_BYTES ((256 * 52 + 50 * 256) * 4)  // K (d-major, pitch 52) + V
#define FSTRIDE 64       // one flag per 256B line

// ---- flag line indices (each its own 256B line) ----
#define FL_X3(l)    (0 + (l))            // x[l] ready: +8/step
#define FL_QKV3(l)  (4 + (l))            // qkv staged: +24/step
#define FL_U3(l, j) (8 + (l) * 8 + (j))  // u[l] ready, 8 replicas: +8/step each
#define FL_FP3(l)   (40 + (l))           // ffn partials: +32/step
#define FL_XF3(j)   (44 + (j))           // xf ready, 8 replicas: +8/step each
#define FL_FC3(j)   (52 + (j))           // fc done, replica bid&7: +32/step each
#define FL_MEM3     60
#define FL_CA3      61

// ---- float offsets in d_ws (flow path); flags occupy words 0..4095 ----
#define WS_MEM3 4096     // 2048
#define WS_CA3  6144     // 8192
#define WS_XB3  14336    // 4 x 2048 = 8192
#define WS_XF3  22528    // 2048
#define WS_QB3  24576    // 2048
#define WS_KV3  26624    // k 2048 + v 2048
#define WS_U3   30720    // 4 x 2048 = 8192
#define WS_FFP3 38912    // 2 x 65536 = 131072
#define WS_PV3  169984   // 2048
#define WS_PI3  172032   // 2048 ints

// ---- fallback (round-1 proven) offsets ----
#define WS_MEM 0
#define WS_CA  2048
#define WS_X   10240
#define WS_Q   12288
#define WS_FFP 14336
#define WS_KC  79872
#define WS_VC  489472
#define WS_PV  899072
#define WS_PI  905472
#define WS_TOK 911872
#define FCT 786

// ---------- LLC-coherent helpers ----------
__device__ __forceinline__ float gld(const float* p) {
  return __hip_atomic_load(const_cast<float*>(p), __ATOMIC_RELAXED, __HIP_MEMORY_SCOPE_AGENT);
}
__device__ __forceinline__ void gst(float* p, float v) {
  __hip_atomic_store(p, v, __ATOMIC_RELAXED, __HIP_MEMORY_SCOPE_AGENT);
}
__device__ __forceinline__ int gldi(const int* p) {
  return __hip_atomic_load(const_cast<int*>(p), __ATOMIC_RELAXED, __HIP_MEMORY_SCOPE_AGENT);
}
__device__ __forceinline__ void gsti(int* p, int v) {
  __hip_atomic_store(p, v, __ATOMIC_RELAXED, __HIP_MEMORY_SCOPE_AGENT);
}
__device__ __forceinline__ unsigned fld(unsigned* p) {
  return __hip_atomic_load(p, __ATOMIC_RELAXED, __HIP_MEMORY_SCOPE_AGENT);
}
__device__ __forceinline__ void bump(unsigned* f) {
  asm volatile("s_waitcnt vmcnt(0)" ::: "memory");
  __syncthreads();
  if (threadIdx.x == 0)
    __hip_atomic_fetch_add(f, 1u, __ATOMIC_RELAXED, __HIP_MEMORY_SCOPE_AGENT);
}
// drain + bump 8 replicated lines (stride FSTRIDE apart starting at f)
__device__ __forceinline__ void bump8(unsigned* f) {
  asm volatile("s_waitcnt vmcnt(0)" ::: "memory");
  __syncthreads();
  if (threadIdx.x == 0)
    for (int j = 0; j < 8; ++j)
      __hip_atomic_fetch_add(f + j * FSTRIDE, 1u, __ATOMIC_RELAXED, __HIP_MEMORY_SCOPE_AGENT);
}
__device__ __forceinline__ void waitf(unsigned* f, unsigned tgt) {
  if (threadIdx.x == 0) {
    while (fld(f) < tgt) __builtin_amdgcn_s_sleep(4);
  }
  __syncthreads();
}

__device__ __forceinline__ float block_ln256(float v, int tid, float* red8, float g, float bta) {
  float s = v, s2 = v * v;
#pragma unroll
  for (int m = 32; m >= 1; m >>= 1) { s += __shfl_xor(s, m); s2 += __shfl_xor(s2, m); }
  int w = tid >> 6;
  __syncthreads();
  if ((tid & 63) == 0) { red8[w] = s; red8[4 + w] = s2; }
  __syncthreads();
  s = red8[0] + red8[1] + red8[2] + red8[3];
  s2 = red8[4] + red8[5] + red8[6] + red8[7];
  float mn = s * (1.0f / 256.0f);
  float var = s2 * (1.0f / 256.0f) - mn * mn;
  float rs = rsqrtf(var + LNEPS);
  return (v - mn) * rs * g + bta;
}

// fc GEMV + per-block argmax partial (numerics identical to proven path)
__device__ __forceinline__ void fc_phase(int bid, int tid, int t,
                                         const float* xf, const float* fc_w,
                                         const float* fc_b, float* out,
                                         float* pv, int* pi,
                                         float* xl, float* rv, int* ri) {
  for (int b = 0; b < 8; ++b) xl[b * 260 + tid] = gld(xf + b * 256 + tid);
  __syncthreads();
  int r = tid >> 3, b = tid & 7;
  float bv = -3e38f; int bi = 2147483647;
  int base = bid * RPB;
  for (int i = 0; i < 7; ++i) {
    int rr = i * 32 + r, row = base + rr;
    if (rr < RPB && row < NV) {
      float acc = fc_b[row];
      const float4* w4 = reinterpret_cast<const float4*>(fc_w + (size_t)row * 256);
      const float4* xv = reinterpret_cast<const float4*>(xl + b * 260);
      for (int k = 0; k < 64; ++k) {
        float4 wv = w4[k]; float4 xq = xv[k];
        acc += wv.x * xq.x + wv.y * xq.y + wv.z * xq.z + wv.w * xq.w;
      }
      out[(size_t)(b * 49 + t) * NV + row] = acc;
      if (acc > bv || (acc == bv && row < bi)) { bv = acc; bi = row; }
    }
  }
  rv[tid] = bv; ri[tid] = bi;
  __syncthreads();
  for (int off = 128; off >= 8; off >>= 1) {
    if (tid < off) {
      float v = rv[tid + off]; int id = ri[tid + off];
      if (v > rv[tid] || (v == rv[tid] && id < ri[tid])) { rv[tid] = v; ri[tid] = id; }
    }
    __syncthreads();
  }
  if (tid < 8) { gst(pv + bid * 8 + tid, rv[tid]); gsti(pi + bid * 8 + tid, ri[tid]); }
}

// ================= single-dispatch dataflow kernel v3 =================
__global__ __launch_bounds__(256) void k_flow3(
    const float* __restrict__ emb, const float* __restrict__ w_proj, const float* __restrict__ b_proj,
    const float* __restrict__ tok_emb, const float* __restrict__ pos_enc,
    const float* __restrict__ sa_in_w, const float* __restrict__ sa_in_b,
    const float* __restrict__ sa_out_w, const float* __restrict__ sa_out_b,
    const float* __restrict__ ca_in_w, const float* __restrict__ ca_in_b,
    const float* __restrict__ ca_out_w, const float* __restrict__ ca_out_b,
    const float* __restrict__ ff1_w, const float* __restrict__ ff1_b,
    const float* __restrict__ ff2_w, const float* __restrict__ ff2_b,
    const float* __restrict__ ln_g, const float* __restrict__ ln_b,
    const float* __restrict__ fc_w, const float* __restrict__ fc_b,
    float* __restrict__ out, float* __restrict__ wsf, int* __restrict__ wsi) {
  extern __shared__ float dynlds[];   // ATTN: K [256][52] d-major + V [50][256]
  const int bid = blockIdx.x, tid = threadIdx.x;

  unsigned* FL = (unsigned*)wsf;
  float* mem = wsf + WS_MEM3;
  float* ca  = wsf + WS_CA3;
  float* xb  = wsf + WS_XB3;   // x[l] = xb + l*2048
  float* xf  = wsf + WS_XF3;
  float* qb  = wsf + WS_QB3;
  float* kv  = wsf + WS_KV3;   // k: [b][256]; v at +2048
  float* u   = wsf + WS_U3;    // u[l] = u + l*2048
  float* ffp = wsf + WS_FFP3;  // parity(l&1)*65536
  float* pv  = wsf + WS_PV3;
  int*   pi  = wsi + WS_PI3;

  __shared__ float xl[8 * 260];
  __shared__ float h1l[64 * 9];
  __shared__ float ql[256], ol[256], ph[8 * 64];
  __shared__ float red8[8];
  __shared__ float rv[256];
  __shared__ int   ri[256];
  __shared__ float el[1536];

  // ---- init 1: mem = embedding @ w_proj.T + b_proj (blocks 0..63)
  if (bid < 64) {
    int b = bid >> 3, tile = bid & 7;
    for (int k = tid; k < 1536; k += 256) el[k] = emb[b * 1536 + k];
    __syncthreads();
    int r = tid >> 3, g = tid & 7;
    int row = tile * 32 + r;
    float acc = 0.f;
    const float* wr = w_proj + (size_t)row * 1536;
    for (int c = g * 192; c < g * 192 + 192; ++c) acc += wr[c] * el[c];
    rv[tid] = acc;
    __syncthreads();
    for (int off = 4; off >= 1; off >>= 1) {
      if (g < off) rv[tid] += rv[tid + off];
      __syncthreads();
    }
    if (g == 0) gst(mem + b * 256 + row, rv[tid] + b_proj[row]);
    bump(FL + FL_MEM3 * FSTRIDE);
  }
  // ---- init 2: cross-attn constant (memory len 1 => attn == V_mem) (blocks 64..95)
  if (bid >= 64 && bid < 96) {
    waitf(FL + FL_MEM3 * FSTRIDE, 64u);
    int l = (bid - 64) >> 3, b = (bid - 64) & 7;
    ql[tid] = gld(mem + b * 256 + tid);
    __syncthreads();
    float acc = ca_in_b[l * 768 + 512 + tid];
    const float* wr = ca_in_w + (size_t)(l * 768 + 512 + tid) * 256;
    for (int c = 0; c < 256; ++c) acc += wr[c] * ql[c];
    ol[tid] = acc;
    __syncthreads();
    float acc2 = ca_out_b[l * 256 + tid];
    const float* wr2 = ca_out_w + (size_t)(l * 256 + tid) * 256;
    for (int c = 0; c < 256; ++c) acc2 += wr2[c] * ol[c];
    gst(ca + (l * 8 + b) * 256 + tid, acc2);
    bump(FL + FL_CA3 * FSTRIDE);
  }

  if (bid < 24) {
    // ======= QKV role: 32 rows of the 768 qkv rows, all batches, per layer =======
    for (int t = 0; t < NSTEP; ++t) {
      for (int l = 0; l < 4; ++l) {
        waitf(FL + FL_X3(l) * FSTRIDE, 8u * (unsigned)(t + 1));
        for (int b = 0; b < 8; ++b) xl[b * 260 + tid] = gld(xb + l * 2048 + b * 256 + tid);
        __syncthreads();
        int r = tid >> 3, b8 = tid & 7;
        int row = bid * 32 + r;
        float acc = sa_in_b[l * 768 + row];
        const float4* w4 = reinterpret_cast<const float4*>(sa_in_w + (size_t)(l * 768 + row) * 256);
        const float4* xv = reinterpret_cast<const float4*>(xl + b8 * 260);
#pragma unroll 8
        for (int k = 0; k < 64; ++k) {
          float4 wv = w4[k]; float4 xq = xv[k];
          acc += wv.x * xq.x + wv.y * xq.y + wv.z * xq.z + wv.w * xq.w;
        }
        if (row < 256) gst(qb + b8 * 256 + row, acc);
        else if (row < 512) gst(kv + b8 * 256 + (row - 256), acc);
        else gst(kv + 2048 + b8 * 256 + (row - 512), acc);
        bump(FL + FL_QKV3(l) * FSTRIDE);
      }
      waitf(FL + FL_XF3(bid & 7) * FSTRIDE, 8u * (unsigned)(t + 1));
      fc_phase(bid, tid, t, xf, fc_w, fc_b, out, pv, pi, xl, rv, ri);
      bump(FL + FL_FC3(bid & 7) * FSTRIDE);
    }
  } else if (bid < 32) {
    // ======= XRED role: batch b = bid-24. argmax+embed, FFN reduce+LN, final LN =======
    int b = bid - 24;
    for (int t = 0; t < NSTEP; ++t) {
      int tokb;
      if (t > 0) {
        if (tid == 0) {
          for (;;) {
            unsigned s = 0;
            for (int j = 0; j < 8; ++j) s += fld(FL + FL_FC3(j) * FSTRIDE);
            if (s >= 256u * (unsigned)t) break;
            __builtin_amdgcn_s_sleep(4);
          }
        }
        __syncthreads();
        rv[tid] = gld(pv + tid * 8 + b); ri[tid] = gldi(pi + tid * 8 + b);
        __syncthreads();
        for (int off = 128; off >= 1; off >>= 1) {
          if (tid < off) {
            float v = rv[tid + off]; int id = ri[tid + off];
            if (v > rv[tid] || (v == rv[tid] && id < ri[tid])) { rv[tid] = v; ri[tid] = id; }
          }
          __syncthreads();
        }
        tokb = ri[0];
      } else {
        tokb = BOSTOK;
      }
      float x0 = tok_emb[(size_t)tokb * 256 + tid] + pos_enc[t * 256 + tid];
      gst(xb + b * 256 + tid, x0);
      bump(FL + FL_X3(0) * FSTRIDE);
      for (int l = 0; l < 4; ++l) {
        waitf(FL + FL_FP3(l) * FSTRIDE, 32u * (unsigned)(t + 1));
        float a = gld(u + l * 2048 + b * 256 + tid) + ff2_b[l * 256 + tid];
        int par = l & 1;
        for (int s = 0; s < 32; ++s) a += gld(ffp + par * 65536 + (s * 8 + b) * 256 + tid);
        float y = block_ln256(a, tid, red8, ln_g[(l * 3 + 2) * 256 + tid],
                              ln_b[(l * 3 + 2) * 256 + tid]);
        if (l < 3) {
          gst(xb + (l + 1) * 2048 + b * 256 + tid, y);
          bump(FL + FL_X3(l + 1) * FSTRIDE);
        } else {
          gst(xf + b * 256 + tid, y);
          bump8(FL + FL_XF3(0) * FSTRIDE);
        }
      }
      waitf(FL + FL_XF3(bid & 7) * FSTRIDE, 8u * (unsigned)(t + 1));
      fc_phase(bid, tid, t, xf, fc_w, fc_b, out, pv, pi, xl, rv, ri);
      bump(FL + FL_FC3(bid & 7) * FSTRIDE);
    }
  } else if (bid < 64) {
    // ======= ATTN role: (myl, myb); persistent K/V in LDS; attn + out-proj + LN0+ca+LN1 =======
    int myl = (bid - 32) >> 3, myb = (bid - 32) & 7;
    float* Klds = dynlds;             // [256][52] d-major
    float* Vlds = dynlds + 256 * 52;  // [50][256]
    waitf(FL + FL_CA3 * FSTRIDE, 32u);
    for (int t = 0; t < NSTEP; ++t) {
      waitf(FL + FL_QKV3(myl) * FSTRIDE, 24u * (unsigned)(t + 1));
      float kval = gld(kv + myb * 256 + tid);
      float vval = gld(kv + 2048 + myb * 256 + tid);
      ql[tid] = gld(qb + myb * 256 + tid);
      float xres = gld(xb + myl * 2048 + myb * 256 + tid);
      Klds[tid * 52 + t] = kval;
      Vlds[t * 256 + tid] = vval;
      __syncthreads();
      int h = tid >> 5, j0 = tid & 31;
      const float* qh = ql + h * 32;
      float s0 = -3e38f, s1 = -3e38f;
      if (j0 <= t) {
        float d0 = 0.f;
#pragma unroll
        for (int d = 0; d < 32; ++d) d0 += qh[d] * Klds[(h * 32 + d) * 52 + j0];
        s0 = d0 * 0.17677669529663687f;
      }
      if (j0 + 32 <= t) {
        float d1 = 0.f;
#pragma unroll
        for (int d = 0; d < 32; ++d) d1 += qh[d] * Klds[(h * 32 + d) * 52 + j0 + 32];
        s1 = d1 * 0.17677669529663687f;
      }
      float mx = fmaxf(s0, s1);
      for (int m = 16; m >= 1; m >>= 1) mx = fmaxf(mx, __shfl_xor(mx, m, 32));
      float e0 = (j0 <= t) ? expf(s0 - mx) : 0.f;
      float e1 = (j0 + 32 <= t) ? expf(s1 - mx) : 0.f;
      float sm = e0 + e1;
      for (int m = 16; m >= 1; m >>= 1) sm += __shfl_xor(sm, m, 32);
      ph[h * 64 + j0] = e0;
      ph[h * 64 + j0 + 32] = e1;
      __syncthreads();
      float o = 0.f;
      for (int j = 0; j <= t; ++j) o += ph[h * 64 + j] * Vlds[j * 256 + tid];
      ol[tid] = o / sm;
      __syncthreads();
      float acc = sa_out_b[myl * 256 + tid];
      const float4* w4 = reinterpret_cast<const float4*>(sa_out_w + (size_t)(myl * 256 + tid) * 256);
#pragma unroll 4
      for (int k = 0; k < 64; ++k) {
        float4 wv = w4[k];
        acc += wv.x * ol[4 * k] + wv.y * ol[4 * k + 1] + wv.z * ol[4 * k + 2] + wv.w * ol[4 * k + 3];
      }
      acc += xres;
      float y = block_ln256(acc, tid, red8, ln_g[(myl * 3 + 0) * 256 + tid],
                            ln_b[(myl * 3 + 0) * 256 + tid]);
      float y2 = block_ln256(y + gld(ca + (myl * 8 + myb) * 256 + tid), tid, red8,
                             ln_g[(myl * 3 + 1) * 256 + tid], ln_b[(myl * 3 + 1) * 256 + tid]);
      gst(u + myl * 2048 + myb * 256 + tid, y2);
      bump8(FL + FL_U3(myl, 0) * FSTRIDE);
      waitf(FL + FL_XF3(bid & 7) * FSTRIDE, 8u * (unsigned)(t + 1));
      fc_phase(bid, tid, t, xf, fc_w, fc_b, out, pv, pi, xl, rv, ri);
      bump(FL + FL_FC3(bid & 7) * FSTRIDE);
    }
  } else if (bid < 96) {
    // ======= FFN role: slice s = bid-64 (64 neurons), per layer =======
    int s = bid - 64;
    for (int t = 0; t < NSTEP; ++t) {
      for (int l = 0; l < 4; ++l) {
        waitf(FL + FL_U3(l, bid & 7) * FSTRIDE, 8u * (unsigned)(t + 1));
        for (int b = 0; b < 8; ++b) xl[b * 260 + tid] = gld(u + l * 2048 + b * 256 + tid);
        __syncthreads();
        int n0 = tid >> 3, b = tid & 7;
#pragma unroll
        for (int i = 0; i < 2; ++i) {
          int nn = n0 + i * 32, row = s * 64 + nn;
          float acc = ff1_b[l * 2048 + row];
          const float4* w4 = reinterpret_cast<const float4*>(ff1_w + (size_t)(l * 2048 + row) * 256);
          const float4* xv = reinterpret_cast<const float4*>(xl + b * 260);
          for (int k = 0; k < 64; ++k) {
            float4 wv = w4[k]; float4 xq = xv[k];
            acc += wv.x * xq.x + wv.y * xq.y + wv.z * xq.z + wv.w * xq.w;
          }
          h1l[nn * 9 + b] = fmaxf(acc, 0.f);
        }
        __syncthreads();
        float facc[8] = {0, 0, 0, 0, 0, 0, 0, 0};
        const float* w2p = ff2_w + (size_t)(l * 256 + tid) * 2048 + s * 64;
        for (int n = 0; n < 64; ++n) {
          float wv = w2p[n];
#pragma unroll
          for (int b2 = 0; b2 < 8; ++b2) facc[b2] += wv * h1l[n * 9 + b2];
        }
        int par = l & 1;
        for (int b2 = 0; b2 < 8; ++b2)
          gst(ffp + par * 65536 + (s * 8 + b2) * 256 + tid, facc[b2]);
        bump(FL + FL_FP3(l) * FSTRIDE);
      }
      waitf(FL + FL_XF3(bid & 7) * FSTRIDE, 8u * (unsigned)(t + 1));
      fc_phase(bid, tid, t, xf, fc_w, fc_b, out, pv, pi, xl, rv, ri);
      bump(FL + FL_FC3(bid & 7) * FSTRIDE);
    }
  } else {
    // ======= fc-only role =======
    for (int t = 0; t < NSTEP; ++t) {
      waitf(FL + FL_XF3(bid & 7) * FSTRIDE, 8u * (unsigned)(t + 1));
      fc_phase(bid, tid, t, xf, fc_w, fc_b, out, pv, pi, xl, rv, ri);
      bump(FL + FL_FC3(bid & 7) * FSTRIDE);
    }
  }
}

// ================= fallback path (round-1, proven at 13.7 ms) =================
__device__ __forceinline__ float block_ln(float v, int tid, float* red, float* red2,
                                          float g, float bta) {
  red[tid] = v; red2[tid] = v * v;
  __syncthreads();
  for (int off = 128; off > 0; off >>= 1) {
    if (tid < off) { red[tid] += red[tid + off]; red2[tid] += red2[tid + off]; }
    __syncthreads();
  }
  float m = red[0] * (1.0f / 256.0f);
  float var = red2[0] * (1.0f / 256.0f) - m * m;
  float rs = rsqrtf(var + LNEPS);
  float y = (v - m) * rs * g + bta;
  __syncthreads();
  return y;
}

__global__ __launch_bounds__(256) void k_mem(const float* __restrict__ emb,
                                             const float* __restrict__ w,
                                             const float* __restrict__ bias,
                                             float* __restrict__ mem) {
  __shared__ float el[1536];
  __shared__ float red[256];
  int b = blockIdx.x >> 3, tile = blockIdx.x & 7, tid = threadIdx.x;
  for (int k = tid; k < 1536; k += 256) el[k] = emb[b * 1536 + k];
  __syncthreads();
  int r = tid >> 3, g = tid & 7;
  int row = tile * 32 + r;
  float acc = 0.f;
  const float* wr = w + row * 1536;
  for (int c = g * 192; c < g * 192 + 192; ++c) acc += wr[c] * el[c];
  red[tid] = acc;
  __syncthreads();
  for (int off = 4; off >= 1; off >>= 1) {
    if (g < off) red[tid] += red[tid + off];
    __syncthreads();
  }
  if (g == 0) mem[b * 256 + row] = red[tid] + bias[row];
}

__global__ __launch_bounds__(256) void k_ca(const float* __restrict__ mem,
                                            const float* __restrict__ iw,
                                            const float* __restrict__ ib,
                                            const float* __restrict__ ow,
                                            const float* __restrict__ ob,
                                            float* __restrict__ ca) {
  __shared__ float ml[256], vl[256];
  int l = blockIdx.x >> 3, b = blockIdx.x & 7, tid = threadIdx.x;
  ml[tid] = mem[b * 256 + tid];
  __syncthreads();
  float acc = ib[l * 768 + 512 + tid];
  const float* wr = iw + (size_t)(l * 768 + 512 + tid) * 256;
  for (int c = 0; c < 256; ++c) acc += wr[c] * ml[c];
  vl[tid] = acc;
  __syncthreads();
  float acc2 = ob[l * 256 + tid];
  const float* wr2 = ow + (size_t)(l * 256 + tid) * 256;
  for (int c = 0; c < 256; ++c) acc2 += wr2[c] * vl[c];
  ca[(l * 8 + b) * 256 + tid] = acc2;
}

__global__ void k_tok_init(int* __restrict__ tok) {
  if (threadIdx.x < 8) tok[threadIdx.x * 64] = BOSTOK;
}

__global__ __launch_bounds__(256) void k_embed(const int* __restrict__ tok,
                                               const float* __restrict__ te,
                                               const float* __restrict__ pe,
                                               float* __restrict__ x, int t) {
  int tid = threadIdx.x;
  for (int b = 0; b < 8; ++b) {
    int tk = tok[b * 64 + t];
    x[b * 256 + tid] = te[(size_t)tk * 256 + tid] + pe[t * 256 + tid];
  }
}

__global__ __launch_bounds__(256) void k_qkv(const float* __restrict__ x,
                                             const float* __restrict__ w,
                                             const float* __restrict__ bias,
                                             float* __restrict__ q,
                                             float* __restrict__ kc,
                                             float* __restrict__ vc, int l, int t) {
  __shared__ float xl[8 * 260];
  int tid = threadIdx.x;
  for (int k = 0; k < 8; ++k) {
    int idx = tid + k * 256;
    xl[(idx >> 8) * 260 + (idx & 255)] = x[idx];
  }
  __syncthreads();
  int r = tid >> 3, b = tid & 7;
  int row = blockIdx.x * 32 + r;
  float acc = bias[l * 768 + row];
  const float4* w4 = reinterpret_cast<const float4*>(w + (size_t)(l * 768 + row) * 256);
  const float4* xv = reinterpret_cast<const float4*>(xl + b * 260);
#pragma unroll 8
  for (int k = 0; k < 64; ++k) {
    float4 wv = w4[k]; float4 xq = xv[k];
    acc += wv.x * xq.x + wv.y * xq.y + wv.z * xq.z + wv.w * xq.w;
  }
  if (row < 256) {
    q[b * 256 + row] = acc;
  } else if (row < 512) {
    int h = (row - 256) >> 5, d = (row - 256) & 31;
    kc[(((l * 8 + b) * 8 + h) * 50 + t) * 32 + d] = acc;
  } else {
    int h = (row - 512) >> 5, d = (row - 512) & 31;
    vc[(((l * 8 + b) * 8 + h) * 50 + t) * 32 + d] = acc;
  }
}

__global__ __launch_bounds__(256) void k_attn(const float* __restrict__ q,
                                              float* __restrict__ x,
                                              const float* __restrict__ kc,
                                              const float* __restrict__ vc,
                                              const float* __restrict__ ow,
                                              const float* __restrict__ ob,
                                              const float* __restrict__ lg,
                                              const float* __restrict__ lb,
                                              const float* __restrict__ ca, int l, int t) {
  __shared__ float ql[256], ol[256], sc[64], red[256], red2[256];
  __shared__ float ssum;
  int b = blockIdx.x, tid = threadIdx.x;
  float xres = x[b * 256 + tid];
  ql[tid] = q[b * 256 + tid];
  __syncthreads();
  for (int h = 0; h < 8; ++h) {
    const float* kb = kc + (size_t)(((l * 8 + b) * 8 + h) * 50) * 32;
    if (tid <= t) {
      float s = 0.f;
      const float* kr = kb + tid * 32;
#pragma unroll
      for (int d = 0; d < 32; ++d) s += ql[h * 32 + d] * kr[d];
      sc[tid] = s * 0.17677669529663687f;
    }
    __syncthreads();
    if (tid < 64) {
      float v = (tid <= t) ? sc[tid] : -1e30f;
      float mx = v;
      for (int m = 32; m >= 1; m >>= 1) mx = fmaxf(mx, __shfl_xor(mx, m));
      float e = (tid <= t) ? expf(sc[tid] - mx) : 0.f;
      sc[tid] = e;
      float sm = e;
      for (int m = 32; m >= 1; m >>= 1) sm += __shfl_xor(sm, m);
      if (tid == 0) ssum = sm;
    }
    __syncthreads();
    if (tid < 32) {
      const float* vb = vc + (size_t)(((l * 8 + b) * 8 + h) * 50) * 32 + tid;
      float acc = 0.f;
      for (int j = 0; j <= t; ++j) acc += sc[j] * vb[j * 32];
      ol[h * 32 + tid] = acc / ssum;
    }
    __syncthreads();
  }
  float acc = ob[l * 256 + tid];
  const float4* w4 = reinterpret_cast<const float4*>(ow + (size_t)(l * 256 + tid) * 256);
#pragma unroll 4
  for (int k = 0; k < 64; ++k) {
    float4 wv = w4[k];
    acc += wv.x * ol[4 * k] + wv.y * ol[4 * k + 1] + wv.z * ol[4 * k + 2] + wv.w * ol[4 * k + 3];
  }
  acc += xres;
  float y = block_ln(acc, tid, red, red2, lg[(l * 3 + 0) * 256 + tid], lb[(l * 3 + 0) * 256 + tid]);
  float acc2 = y + ca[(l * 8 + b) * 256 + tid];
  float y2 = block_ln(acc2, tid, red, red2, lg[(l * 3 + 1) * 256 + tid], lb[(l * 3 + 1) * 256 + tid]);
  x[b * 256 + tid] = y2;
}

__global__ __launch_bounds__(256) void k_ffn(const float* __restrict__ x,
                                             const float* __restrict__ w1,
                                             const float* __restrict__ b1,
                                             const float* __restrict__ w2,
                                             float* __restrict__ ffp, int l) {
  __shared__ float xl[8 * 260];
  __shared__ float h1l[64 * 9];
  int tid = threadIdx.x, s = blockIdx.x;
  for (int k = 0; k < 8; ++k) {
    int idx = tid + k * 256;
    xl[(idx >> 8) * 260 + (idx & 255)] = x[idx];
  }
  __syncthreads();
  int n0 = tid >> 3, b = tid & 7;
#pragma unroll
  for (int i = 0; i < 2; ++i) {
    int nn = n0 + i * 32, row = s * 64 + nn;
    float acc = b1[l * 2048 + row];
    const float4* w4 = reinterpret_cast<const float4*>(w1 + (size_t)(l * 2048 + row) * 256);
    const float4* xv = reinterpret_cast<const float4*>(xl + b * 260);
    for (int k = 0; k < 64; ++k) {
      float4 wv = w4[k]; float4 xq = xv[k];
      acc += wv.x * xq.x + wv.y * xq.y + wv.z * xq.z + wv.w * xq.w;
    }
    h1l[nn * 9 + b] = fmaxf(acc, 0.f);
  }
  __syncthreads();
  int row = tid;
  float acc[8] = {0, 0, 0, 0, 0, 0, 0, 0};
  const float* w2p = w2 + (size_t)(l * 256 + row) * 2048 + s * 64;
  for (int n = 0; n < 64; ++n) {
    float wv = w2p[n];
#pragma unroll
    for (int b2 = 0; b2 < 8; ++b2) acc[b2] += wv * h1l[n * 9 + b2];
  }
  for (int b2 = 0; b2 < 8; ++b2) ffp[(s * 8 + b2) * 256 + row] = acc[b2];
}

__global__ __launch_bounds__(256) void k_ffred(float* __restrict__ x,
                                               const float* __restrict__ ffp,
                                               const float* __restrict__ b2,
                                               const float* __restrict__ lg,
                                               const float* __restrict__ lb, int l) {
  __shared__ float red[256], red2[256];
  int b = blockIdx.x, tid = threadIdx.x;
  float acc = b2[l * 256 + tid] + x[b * 256 + tid];
  for (int s = 0; s < 32; ++s) acc += ffp[(s * 8 + b) * 256 + tid];
  float y = block_ln(acc, tid, red, red2, lg[(l * 3 + 2) * 256 + tid], lb[(l * 3 + 2) * 256 + tid]);
  x[b * 256 + tid] = y;
}

__global__ __launch_bounds__(256) void k_fc(const float* __restrict__ h,
                                            const float* __restrict__ w,
                                            const float* __restrict__ bias,
                                            float* __restrict__ out,
                                            float* __restrict__ pv,
                                            int* __restrict__ pi, int t) {
  __shared__ float hl[8 * 260];
  __shared__ float rv[256];
  __shared__ int ri[256];
  int tid = threadIdx.x, wg = blockIdx.x;
  for (int k = 0; k < 8; ++k) {
    int idx = tid + k * 256;
    hl[(idx >> 8) * 260 + (idx & 255)] = h[idx];
  }
  __syncthreads();
  int r = tid >> 3, b = tid & 7;
  float bv = -3e38f;
  int bi = 2147483647;
  for (int i = 0; i < 2; ++i) {
    int row = wg * 64 + i * 32 + r;
    if (row < NV) {
      float acc = bias[row];
      const float4* w4 = reinterpret_cast<const float4*>(w + (size_t)row * 256);
      const float4* xv = reinterpret_cast<const float4*>(hl + b * 260);
      for (int k = 0; k < 64; ++k) {
        float4 wv = w4[k]; float4 xq = xv[k];
        acc += wv.x * xq.x + wv.y * xq.y + wv.z * xq.z + wv.w * xq.w;
      }
      out[(size_t)(b * 49 + t) * NV + row] = acc;
      if (acc > bv || (acc == bv && row < bi)) { bv = acc; bi = row; }
    }
  }
  rv[tid] = bv; ri[tid] = bi;
  __syncthreads();
  for (int off = 128; off >= 8; off >>= 1) {
    if (tid < off) {
      float v = rv[tid + off]; int id = ri[tid + off];
      if (v > rv[tid] || (v == rv[tid] && id < ri[tid])) { rv[tid] = v; ri[tid] = id; }
    }
    __syncthreads();
  }
  if (tid < 8) { pv[wg * 8 + tid] = rv[tid]; pi[wg * 8 + tid] = ri[tid]; }
}

__global__ __launch_bounds__(256) void k_amax(const float* __restrict__ pv,
                                              const int* __restrict__ pi,
                                              int* __restrict__ tok, int t) {
  __shared__ float rv[256];
  __shared__ int ri[256];
  int tid = threadIdx.x, b = tid & 7, i0 = tid >> 3;
  float bv = -3e38f;
  int bi = 2147483647;
  for (int p = i0; p < FCT; p += 32) {
    float v = pv[p * 8 + b]; int id = pi[p * 8 + b];
    if (v > bv || (v == bv && id < bi)) { bv = v; bi = id; }
  }
  rv[tid] = bv; ri[tid] = bi;
  __syncthreads();
  for (int off = 128; off >= 8; off >>= 1) {
    if (tid < off) {
      float v = rv[tid + off]; int id = ri[tid + off];
      if (v > rv[tid] || (v == rv[tid] && id < ri[tid])) { rv[tid] = v; ri[tid] = id; }
    }
    __syncthreads();
  }
  if (tid < 8) tok[tid * 64 + t + 1] = ri[tid];
}

extern "C" void kernel_launch(void* const* d_in, const int* in_sizes, int n_in,
                              void* d_out, int out_size, void* d_ws, size_t ws_size,
                              hipStream_t stream) {
  (void)in_sizes; (void)n_in; (void)out_size; (void)ws_size;
  const float* embedding = (const float*)d_in[0];
  const float* w_proj   = (const float*)d_in[1];
  const float* b_proj   = (const float*)d_in[2];
  const float* tok_emb  = (const float*)d_in[3];
  const float* pos_enc  = (const float*)d_in[4];
  const float* sa_in_w  = (const float*)d_in[5];
  const float* sa_in_b  = (const float*)d_in[6];
  const float* sa_out_w = (const float*)d_in[7];
  const float* sa_out_b = (const float*)d_in[8];
  const float* ca_in_w  = (const float*)d_in[9];
  const float* ca_in_b  = (const float*)d_in[10];
  const float* ca_out_w = (const float*)d_in[11];
  const float* ca_out_b = (const float*)d_in[12];
  const float* ff1_w    = (const float*)d_in[13];
  const float* ff1_b    = (const float*)d_in[14];
  const float* ff2_w    = (const float*)d_in[15];
  const float* ff2_b    = (const float*)d_in[16];
  const float* ln_g     = (const float*)d_in[17];
  const float* ln_b     = (const float*)d_in[18];
  const float* fc_w     = (const float*)d_in[19];
  const float* fc_b     = (const float*)d_in[20];
  float* out = (float*)d_out;
  float* wsf = (float*)d_ws;
  int*   wsi = (int*)d_ws;

  int dev = 0;
  (void)hipGetDevice(&dev);
  int coopAttr = 0;
  (void)hipDeviceGetAttribute(&coopAttr, hipDeviceAttributeCooperativeLaunch, dev);
  int ncu = 0;
  (void)hipDeviceGetAttribute(&ncu, hipDeviceAttributeMultiprocessorCount, dev);
  (void)hipFuncSetAttribute(reinterpret_cast<const void*>(k_flow3),
                            hipFuncAttributeMaxDynamicSharedMemorySize, DYN_LDS_BYTES);
  int maxb = 0;
  hipError_t oe = hipOccupancyMaxActiveBlocksPerMultiprocessor(&maxb, k_flow3, 256, DYN_LDS_BYTES);

  bool coop_ok = (coopAttr != 0) && (oe == hipSuccess) && ((long)maxb * (long)ncu >= NBLK);

  if (coop_ok) {
    (void)hipMemsetAsync(d_ws, 0, 16384, stream);  // zero flag lines
    void* args[] = {
        (void*)&embedding, (void*)&w_proj, (void*)&b_proj, (void*)&tok_emb, (void*)&pos_enc,
        (void*)&sa_in_w, (void*)&sa_in_b, (void*)&sa_out_w, (void*)&sa_out_b,
        (void*)&ca_in_w, (void*)&ca_in_b, (void*)&ca_out_w, (void*)&ca_out_b,
        (void*)&ff1_w, (void*)&ff1_b, (void*)&ff2_w, (void*)&ff2_b,
        (void*)&ln_g, (void*)&ln_b, (void*)&fc_w, (void*)&fc_b,
        (void*)&out, (void*)&wsf, (void*)&wsi};
    hipError_t le = hipLaunchCooperativeKernel((void*)k_flow3, dim3(NBLK), dim3(256),
                                               args, DYN_LDS_BYTES, stream);
    if (le != hipSuccess) coop_ok = false;
  }

  if (!coop_ok) {
    float* mem = wsf + WS_MEM;
    float* ca  = wsf + WS_CA;
    float* x   = wsf + WS_X;
    float* q   = wsf + WS_Q;
    float* ffp = wsf + WS_FFP;
    float* kc  = wsf + WS_KC;
    float* vc  = wsf + WS_VC;
    float* pv  = wsf + WS_PV;
    int*   pi  = wsi + WS_PI;
    int*   tok = wsi + WS_TOK;

    k_mem<<<64, 256, 0, stream>>>(embedding, w_proj, b_proj, mem);
    k_ca<<<32, 256, 0, stream>>>(mem, ca_in_w, ca_in_b, ca_out_w, ca_out_b, ca);
    k_tok_init<<<1, 64, 0, stream>>>(tok);

    for (int t = 0; t < NSTEP; ++t) {
      k_embed<<<1, 256, 0, stream>>>(tok, tok_emb, pos_enc, x, t);
      for (int l = 0; l < 4; ++l) {
        k_qkv<<<24, 256, 0, stream>>>(x, sa_in_w, sa_in_b, q, kc, vc, l, t);
        k_attn<<<8, 256, 0, stream>>>(q, x, kc, vc, sa_out_w, sa_out_b, ln_g, ln_b, ca, l, t);
        k_ffn<<<32, 256, 0, stream>>>(x, ff1_w, ff1_b, ff2_w, ffp, l);
        k_ffred<<<8, 256, 0, stream>>>(x, ffp, ff2_b, ln_g, ln_b, l);
      }
      k_fc<<<FCT, 256, 0, stream>>>(x, fc_w, fc_b, out, pv, pi, t);
      k_amax<<<1, 256, 0, stream>>>(pv, pi, tok, t);
    }
  }
}

// Round 7
// 13629.517 us; speedup vs baseline: 1.0002x; 1.0002x over previous
//
#include <hip/hip_runtime.h>

#define NV 50257
#define BOSTOK 50256
#define LNEPS 1e-5f
#define NSTEP 49
#define NBLK 256
#define RPB 197
#define DYN_LDS_BYTES ((256 * 52 + 50 * 256) * 4)
#define FSTR 64

// flag line indices (each its own 256B line)
#define FQKV(l)   (0 + (l))              // +24/step
#define FU(l)     (4 + (l))              // +8/step
#define FFPX(l,j) (8 + (l) * 8 + (j))    // +8/step per replica
#define FXF(j)    (40 + (j))             // +8/step per replica
#define FFC(j)    (48 + (j))             // +32/step per replica
#define FMEMF     56
#define FCAF      57

// float offsets in d_ws (flow path); flags occupy words 0..4095
#define WS4_MEM 4096
#define WS4_CA  6144
#define WS4_XF  14336
#define WS4_Q   16384
#define WS4_K   18432
#define WS4_V   20480
#define WS4_U   22528    // [l][b][256] -> 4*2048
#define WS4_FFP 30720    // [par][b*256+tid][8] -> 2*16384
#define WS4_PV  63488
#define WS4_PI  65536

// fallback (round-1 proven) offsets
#define WS_MEM 0
#define WS_CA  2048
#define WS_X   10240
#define WS_Q   12288
#define WS_FFP 14336
#define WS_KC  79872
#define WS_VC  489472
#define WS_PV  899072
#define WS_PI  905472
#define WS_TOK 911872
#define FCT 786

// ---------- coherent scalar helpers ----------
__device__ __forceinline__ float gld(const float* p) {
  return __hip_atomic_load(const_cast<float*>(p), __ATOMIC_RELAXED, __HIP_MEMORY_SCOPE_AGENT);
}
__device__ __forceinline__ void gst(float* p, float v) {
  __hip_atomic_store(p, v, __ATOMIC_RELAXED, __HIP_MEMORY_SCOPE_AGENT);
}
__device__ __forceinline__ void gsti(int* p, int v) {
  __hip_atomic_store(p, v, __ATOMIC_RELAXED, __HIP_MEMORY_SCOPE_AGENT);
}
__device__ __forceinline__ unsigned fld(unsigned* p) {
  return __hip_atomic_load(p, __ATOMIC_RELAXED, __HIP_MEMORY_SCOPE_AGENT);
}
__device__ __forceinline__ void bump(unsigned* f) {
  asm volatile("s_waitcnt vmcnt(0)" ::: "memory");
  __syncthreads();
  if (threadIdx.x == 0)
    __hip_atomic_fetch_add(f, 1u, __ATOMIC_RELAXED, __HIP_MEMORY_SCOPE_AGENT);
}
__device__ __forceinline__ void bump8(unsigned* f) {
  asm volatile("s_waitcnt vmcnt(0)" ::: "memory");
  __syncthreads();
  if (threadIdx.x == 0)
    for (int j = 0; j < 8; ++j)
      __hip_atomic_fetch_add(f + j * FSTR, 1u, __ATOMIC_RELAXED, __HIP_MEMORY_SCOPE_AGENT);
}
// wait returning the observed value (data-dependence anchor for pulls)
__device__ __forceinline__ unsigned waitf(unsigned* f, unsigned tgt, unsigned* sh) {
  if (threadIdx.x == 0) {
    unsigned v = fld(f);
    while (v < tgt) { __builtin_amdgcn_s_sleep(1); v = fld(f); }
    *sh = v;
  }
  __syncthreads();
  return *sh;
}
__device__ __forceinline__ unsigned wait_fcsum(unsigned* FL, unsigned tgt, unsigned* sh) {
  if (threadIdx.x == 0) {
    unsigned s;
    for (;;) {
      s = 0;
      for (int j = 0; j < 8; ++j) s += fld(FL + (48 + j) * FSTR);
      if (s >= tgt) break;
      __builtin_amdgcn_s_sleep(1);
    }
    *sh = s;
  }
  __syncthreads();
  return *sh;
}

// ---------- batched LLC pulls (issue N, wait once) ----------
__device__ __forceinline__ void pull2p(float* x, float* y,
    const float* p0, const float* p1, unsigned salt) {
  asm("global_load_dword %0, %2, off sc0 sc1\n\t"
      "global_load_dword %1, %3, off sc0 sc1\n\t"
      "s_waitcnt vmcnt(0)"
      : "=&v"(*x), "=&v"(*y)
      : "v"(p0), "v"(p1), "v"(salt));
}
__device__ __forceinline__ void pull3p(float* x, float* y, float* z,
    const float* p0, const float* p1, const float* p2, unsigned salt) {
  asm("global_load_dword %0, %3, off sc0 sc1\n\t"
      "global_load_dword %1, %4, off sc0 sc1\n\t"
      "global_load_dword %2, %5, off sc0 sc1\n\t"
      "s_waitcnt vmcnt(0)"
      : "=&v"(*x), "=&v"(*y), "=&v"(*z)
      : "v"(p0), "v"(p1), "v"(p2), "v"(salt));
}
__device__ __forceinline__ void pull8p(float r[8],
    const float* p0, const float* p1, const float* p2, const float* p3,
    const float* p4, const float* p5, const float* p6, const float* p7, unsigned salt) {
  float a0, a1, a2, a3, a4, a5, a6, a7;
  asm("global_load_dword %0, %8, off sc0 sc1\n\t"
      "global_load_dword %1, %9, off sc0 sc1\n\t"
      "global_load_dword %2, %10, off sc0 sc1\n\t"
      "global_load_dword %3, %11, off sc0 sc1\n\t"
      "global_load_dword %4, %12, off sc0 sc1\n\t"
      "global_load_dword %5, %13, off sc0 sc1\n\t"
      "global_load_dword %6, %14, off sc0 sc1\n\t"
      "global_load_dword %7, %15, off sc0 sc1\n\t"
      "s_waitcnt vmcnt(0)"
      : "=&v"(a0), "=&v"(a1), "=&v"(a2), "=&v"(a3),
        "=&v"(a4), "=&v"(a5), "=&v"(a6), "=&v"(a7)
      : "v"(p0), "v"(p1), "v"(p2), "v"(p3), "v"(p4), "v"(p5), "v"(p6), "v"(p7), "v"(salt));
  r[0] = a0; r[1] = a1; r[2] = a2; r[3] = a3;
  r[4] = a4; r[5] = a5; r[6] = a6; r[7] = a7;
}
// u + 8 contiguous ffp floats (2x dwordx4) for one row
__device__ __forceinline__ void pull1_2q(float* u, float4* f0, float4* f1,
    const float* pu, const float* pf, unsigned salt) {
  asm("global_load_dword %0, %3, off sc0 sc1\n\t"
      "global_load_dwordx4 %1, %4, off sc0 sc1\n\t"
      "global_load_dwordx4 %2, %4, off offset:16 sc0 sc1\n\t"
      "s_waitcnt vmcnt(0)"
      : "=&v"(*u), "=&v"(*f0), "=&v"(*f1)
      : "v"(pu), "v"(pf), "v"(salt));
}
// 4 rows x 8 floats (2 dwordx4 each)
__device__ __forceinline__ void pull4x8(float4 r[8],
    const float* p0, const float* p1, const float* p2, const float* p3, unsigned salt) {
  float4 a0, a1, a2, a3, a4, a5, a6, a7;
  asm("global_load_dwordx4 %0, %8, off sc0 sc1\n\t"
      "global_load_dwordx4 %1, %8, off offset:16 sc0 sc1\n\t"
      "global_load_dwordx4 %2, %9, off sc0 sc1\n\t"
      "global_load_dwordx4 %3, %9, off offset:16 sc0 sc1\n\t"
      "global_load_dwordx4 %4, %10, off sc0 sc1\n\t"
      "global_load_dwordx4 %5, %10, off offset:16 sc0 sc1\n\t"
      "global_load_dwordx4 %6, %11, off sc0 sc1\n\t"
      "global_load_dwordx4 %7, %11, off offset:16 sc0 sc1\n\t"
      "s_waitcnt vmcnt(0)"
      : "=&v"(a0), "=&v"(a1), "=&v"(a2), "=&v"(a3),
        "=&v"(a4), "=&v"(a5), "=&v"(a6), "=&v"(a7)
      : "v"(p0), "v"(p1), "v"(p2), "v"(p3), "v"(salt));
  r[0] = a0; r[1] = a1; r[2] = a2; r[3] = a3;
  r[4] = a4; r[5] = a5; r[6] = a6; r[7] = a7;
}

__device__ __forceinline__ float block_ln256(float v, int tid, float* red8, float g, float bta) {
  float s = v, s2 = v * v;
#pragma unroll
  for (int m = 32; m >= 1; m >>= 1) { s += __shfl_xor(s, m); s2 += __shfl_xor(s2, m); }
  int w = tid >> 6;
  __syncthreads();
  if ((tid & 63) == 0) { red8[w] = s; red8[4 + w] = s2; }
  __syncthreads();
  s = red8[0] + red8[1] + red8[2] + red8[3];
  s2 = red8[4] + red8[5] + red8[6] + red8[7];
  float mn = s * (1.0f / 256.0f);
  float var = s2 * (1.0f / 256.0f) - mn * mn;
  float rs = rsqrtf(var + LNEPS);
  return (v - mn) * rs * g + bta;
}

// fc GEMV + per-block argmax partial
__device__ __forceinline__ void fc_phase(int bid, int tid, int t, unsigned salt,
                                         const float* xf, const float* fc_w,
                                         const float* fc_b, float* out,
                                         float* pv, int* pi,
                                         float* xl, float* rv, int* ri) {
  {
    float xv8[8];
    pull8p(xv8, xf + 0 * 256 + tid, xf + 1 * 256 + tid, xf + 2 * 256 + tid, xf + 3 * 256 + tid,
           xf + 4 * 256 + tid, xf + 5 * 256 + tid, xf + 6 * 256 + tid, xf + 7 * 256 + tid, salt);
#pragma unroll
    for (int b = 0; b < 8; ++b) xl[b * 260 + tid] = xv8[b];
  }
  __syncthreads();
  int r = tid >> 3, b = tid & 7;
  float bv = -3e38f; int bi = 2147483647;
  int base = bid * RPB;
  for (int i = 0; i < 7; ++i) {
    int rr = i * 32 + r, row = base + rr;
    if (rr < RPB && row < NV) {
      float acc = fc_b[row];
      const float4* w4 = reinterpret_cast<const float4*>(fc_w + (size_t)row * 256);
      const float4* xv = reinterpret_cast<const float4*>(xl + b * 260);
      for (int k = 0; k < 64; ++k) {
        float4 wv = w4[k]; float4 xq = xv[k];
        acc += wv.x * xq.x + wv.y * xq.y + wv.z * xq.z + wv.w * xq.w;
      }
      out[(size_t)(b * 49 + t) * NV + row] = acc;
      if (acc > bv || (acc == bv && row < bi)) { bv = acc; bi = row; }
    }
  }
  rv[tid] = bv; ri[tid] = bi;
  __syncthreads();
  for (int off = 128; off >= 8; off >>= 1) {
    if (tid < off) {
      float v = rv[tid + off]; int id = ri[tid + off];
      if (v > rv[tid] || (v == rv[tid] && id < ri[tid])) { rv[tid] = v; ri[tid] = id; }
    }
    __syncthreads();
  }
  if (tid < 8) { gst(pv + bid * 8 + tid, rv[tid]); gsti(pi + bid * 8 + tid, ri[tid]); }
}

// ================= single-dispatch dataflow kernel v4 =================
__global__ __launch_bounds__(256) void k_flow4(
    const float* __restrict__ emb, const float* __restrict__ w_proj, const float* __restrict__ b_proj,
    const float* __restrict__ tok_emb, const float* __restrict__ pos_enc,
    const float* __restrict__ sa_in_w, const float* __restrict__ sa_in_b,
    const float* __restrict__ sa_out_w, const float* __restrict__ sa_out_b,
    const float* __restrict__ ca_in_w, const float* __restrict__ ca_in_b,
    const float* __restrict__ ca_out_w, const float* __restrict__ ca_out_b,
    const float* __restrict__ ff1_w, const float* __restrict__ ff1_b,
    const float* __restrict__ ff2_w, const float* __restrict__ ff2_b,
    const float* __restrict__ ln_g, const float* __restrict__ ln_b,
    const float* __restrict__ fc_w, const float* __restrict__ fc_b,
    float* __restrict__ out, float* __restrict__ wsf, int* __restrict__ wsi) {
  extern __shared__ float dynlds[];   // ATTN blocks: K [256][52] d-major + V [50][256]
  const int bid = blockIdx.x, tid = threadIdx.x;

  unsigned* FL = (unsigned*)wsf;
  float* mem = wsf + WS4_MEM;
  float* ca  = wsf + WS4_CA;
  float* xf  = wsf + WS4_XF;
  float* qb  = wsf + WS4_Q;
  float* kb  = wsf + WS4_K;
  float* vb  = wsf + WS4_V;
  float* u   = wsf + WS4_U;
  float* ffp = wsf + WS4_FFP;
  float* pv  = wsf + WS4_PV;
  int*   pi  = wsi + WS4_PI;

  __shared__ float xl[8 * 260];
  __shared__ float h1l[256 * 9];
  __shared__ float ql[256], ol[256], ph[8 * 64];
  __shared__ float red8[8];
  __shared__ float rv[256];
  __shared__ int   ri[256];
  __shared__ int   toks[8];
  __shared__ unsigned saltsh;
  __shared__ float el[1536];

  // ---- init 1: mem = embedding @ w_proj.T + b_proj (blocks 0..63)
  if (bid < 64) {
    int b = bid >> 3, tile = bid & 7;
    for (int k = tid; k < 1536; k += 256) el[k] = emb[b * 1536 + k];
    __syncthreads();
    int r = tid >> 3, g = tid & 7;
    int row = tile * 32 + r;
    float acc = 0.f;
    const float* wr = w_proj + (size_t)row * 1536;
    for (int c = g * 192; c < g * 192 + 192; ++c) acc += wr[c] * el[c];
    rv[tid] = acc;
    __syncthreads();
    for (int off = 4; off >= 1; off >>= 1) {
      if (g < off) rv[tid] += rv[tid + off];
      __syncthreads();
    }
    if (g == 0) gst(mem + b * 256 + row, rv[tid] + b_proj[row]);
    bump(FL + FMEMF * FSTR);
  }
  // ---- init 2: cross-attn constant (memory len 1 => attn == V_mem) (blocks 64..95)
  if (bid >= 64 && bid < 96) {
    unsigned s0 = waitf(FL + FMEMF * FSTR, 64u, &saltsh);
    int l = (bid - 64) >> 3, b = (bid - 64) & 7;
    ql[tid] = gld(mem + b * 256 + tid) + 0.f * (float)(s0 & 0);  // salt anchor (no-op)
    __syncthreads();
    float acc = ca_in_b[l * 768 + 512 + tid];
    const float* wr = ca_in_w + (size_t)(l * 768 + 512 + tid) * 256;
    for (int c = 0; c < 256; ++c) acc += wr[c] * ql[c];
    ol[tid] = acc;
    __syncthreads();
    float acc2 = ca_out_b[l * 256 + tid];
    const float* wr2 = ca_out_w + (size_t)(l * 256 + tid) * 256;
    for (int c = 0; c < 256; ++c) acc2 += wr2[c] * ol[c];
    gst(ca + (l * 8 + b) * 256 + tid, acc2);
    bump(FL + FCAF * FSTR);
  }

  if (bid < 32) {
    // ======= ATTN role: (myl,myb). front-LN (redundant) + attention + proj + LNs =======
    int myl = bid >> 3, myb = bid & 7;
    float* Klds = dynlds;
    float* Vlds = dynlds + 256 * 52;
    unsigned sc = waitf(FL + FCAF * FSTR, 32u, &saltsh);
    float caval = gld(ca + ((myl * 8 + myb) * 256 + (int)(sc & 0)) + tid);  // cached for all steps
    for (int t = 0; t < NSTEP; ++t) {
      float xres;
      if (myl == 0) {
        if (t > 0) {
          unsigned s = wait_fcsum(FL, 256u * (unsigned)t, &saltsh);
          float pvv, piv;
          pull2p(&pvv, &piv, pv + tid * 8 + myb, (const float*)(pi + tid * 8 + myb), s);
          rv[tid] = pvv; ri[tid] = __float_as_int(piv);
          __syncthreads();
          for (int off = 128; off >= 1; off >>= 1) {
            if (tid < off) {
              float v = rv[tid + off]; int id = ri[tid + off];
              if (v > rv[tid] || (v == rv[tid] && id < ri[tid])) { rv[tid] = v; ri[tid] = id; }
            }
            __syncthreads();
          }
          if (tid == 0) toks[0] = ri[0];
          __syncthreads();
        } else {
          if (tid == 0) toks[0] = BOSTOK;
          __syncthreads();
        }
        xres = tok_emb[(size_t)toks[0] * 256 + tid] + pos_enc[t * 256 + tid];
      } else {
        unsigned s = waitf(FL + FFPX(myl - 1, bid & 7) * FSTR, 8u * (unsigned)(t + 1), &saltsh);
        float uv; float4 f0, f1;
        int par = (myl - 1) & 1;
        pull1_2q(&uv, &f0, &f1, u + (myl - 1) * 2048 + myb * 256 + tid,
                 ffp + par * 16384 + (myb * 256 + tid) * 8, s);
        float a = uv + ff2_b[(myl - 1) * 256 + tid]
                + f0.x + f0.y + f0.z + f0.w + f1.x + f1.y + f1.z + f1.w;
        xres = block_ln256(a, tid, red8, ln_g[((myl - 1) * 3 + 2) * 256 + tid],
                           ln_b[((myl - 1) * 3 + 2) * 256 + tid]);
      }
      // wait qkv, pull q/k/v for own batch
      unsigned s2 = waitf(FL + FQKV(myl) * FSTR, 24u * (unsigned)(t + 1), &saltsh);
      float qv, kv, vv;
      pull3p(&qv, &kv, &vv, qb + myb * 256 + tid, kb + myb * 256 + tid, vb + myb * 256 + tid, s2);
      ql[tid] = qv;
      Klds[tid * 52 + t] = kv;
      Vlds[t * 256 + tid] = vv;
      __syncthreads();
      int h = tid >> 5, j0 = tid & 31;
      const float* qh = ql + h * 32;
      float s0v = -3e38f, s1v = -3e38f;
      if (j0 <= t) {
        float d0 = 0.f;
#pragma unroll
        for (int d = 0; d < 32; ++d) d0 += qh[d] * Klds[(h * 32 + d) * 52 + j0];
        s0v = d0 * 0.17677669529663687f;
      }
      if (j0 + 32 <= t) {
        float d1 = 0.f;
#pragma unroll
        for (int d = 0; d < 32; ++d) d1 += qh[d] * Klds[(h * 32 + d) * 52 + j0 + 32];
        s1v = d1 * 0.17677669529663687f;
      }
      float mx = fmaxf(s0v, s1v);
      for (int m = 16; m >= 1; m >>= 1) mx = fmaxf(mx, __shfl_xor(mx, m, 32));
      float e0 = (j0 <= t) ? expf(s0v - mx) : 0.f;
      float e1 = (j0 + 32 <= t) ? expf(s1v - mx) : 0.f;
      float sm = e0 + e1;
      for (int m = 16; m >= 1; m >>= 1) sm += __shfl_xor(sm, m, 32);
      ph[h * 64 + j0] = e0;
      ph[h * 64 + j0 + 32] = e1;
      __syncthreads();
      float o = 0.f;
      for (int j = 0; j <= t; ++j) o += ph[h * 64 + j] * Vlds[j * 256 + tid];
      ol[tid] = o / sm;
      __syncthreads();
      float acc = sa_out_b[myl * 256 + tid];
      const float4* w4 = reinterpret_cast<const float4*>(sa_out_w + (size_t)(myl * 256 + tid) * 256);
#pragma unroll 4
      for (int k = 0; k < 64; ++k) {
        float4 wv = w4[k];
        acc += wv.x * ol[4 * k] + wv.y * ol[4 * k + 1] + wv.z * ol[4 * k + 2] + wv.w * ol[4 * k + 3];
      }
      acc += xres;
      float y = block_ln256(acc, tid, red8, ln_g[(myl * 3 + 0) * 256 + tid],
                            ln_b[(myl * 3 + 0) * 256 + tid]);
      float y2 = block_ln256(y + caval, tid, red8,
                             ln_g[(myl * 3 + 1) * 256 + tid], ln_b[(myl * 3 + 1) * 256 + tid]);
      gst(u + myl * 2048 + myb * 256 + tid, y2);
      bump(FL + FU(myl) * FSTR);

      if (myl == 0) {
        // xf: final LN after layer-3 FFN
        unsigned s3 = waitf(FL + FFPX(3, bid & 7) * FSTR, 8u * (unsigned)(t + 1), &saltsh);
        float uv; float4 f0, f1;
        pull1_2q(&uv, &f0, &f1, u + 3 * 2048 + myb * 256 + tid,
                 ffp + 1 * 16384 + (myb * 256 + tid) * 8, s3);  // par(l=3)=1
        float a = uv + ff2_b[3 * 256 + tid]
                + f0.x + f0.y + f0.z + f0.w + f1.x + f1.y + f1.z + f1.w;
        float xfv = block_ln256(a, tid, red8, ln_g[(3 * 3 + 2) * 256 + tid],
                                ln_b[(3 * 3 + 2) * 256 + tid]);
        gst(xf + myb * 256 + tid, xfv);
        bump8(FL + FXF(0) * FSTR);
      }
      unsigned s4 = waitf(FL + FXF(bid & 7) * FSTR, 8u * (unsigned)(t + 1), &saltsh);
      fc_phase(bid, tid, t, s4, xf, fc_w, fc_b, out, pv, pi, xl, rv, ri);
      bump(FL + FFC(bid & 7) * FSTR);
    }
  } else if (bid < 56) {
    // ======= QKV role: 32 rows of 768; redundant x-compute (argmax/LN) =======
    int qi = bid - 32;
    for (int t = 0; t < NSTEP; ++t) {
      for (int l = 0; l < 4; ++l) {
        if (l == 0) {
          if (t == 0) {
            if (tid < 8) toks[tid] = BOSTOK;
            __syncthreads();
          } else {
            unsigned s = wait_fcsum(FL, 256u * (unsigned)t, &saltsh);
            int i0 = tid >> 3, b = tid & 7;
            float pvv[8], piv[8];
            pull8p(pvv, pv + (i0 + 0) * 8 + b, pv + (i0 + 32) * 8 + b, pv + (i0 + 64) * 8 + b,
                   pv + (i0 + 96) * 8 + b, pv + (i0 + 128) * 8 + b, pv + (i0 + 160) * 8 + b,
                   pv + (i0 + 192) * 8 + b, pv + (i0 + 224) * 8 + b, s);
            const float* pif = (const float*)pi;
            pull8p(piv, pif + (i0 + 0) * 8 + b, pif + (i0 + 32) * 8 + b, pif + (i0 + 64) * 8 + b,
                   pif + (i0 + 96) * 8 + b, pif + (i0 + 128) * 8 + b, pif + (i0 + 160) * 8 + b,
                   pif + (i0 + 192) * 8 + b, pif + (i0 + 224) * 8 + b, s);
            float bv = -3e38f; int bi = 2147483647;
#pragma unroll
            for (int k = 0; k < 8; ++k) {
              float v = pvv[k]; int id = __float_as_int(piv[k]);
              if (v > bv || (v == bv && id < bi)) { bv = v; bi = id; }
            }
            rv[tid] = bv; ri[tid] = bi;
            __syncthreads();
            for (int off = 128; off >= 8; off >>= 1) {
              if (tid < off) {
                float v = rv[tid + off]; int id = ri[tid + off];
                if (v > rv[tid] || (v == rv[tid] && id < ri[tid])) { rv[tid] = v; ri[tid] = id; }
              }
              __syncthreads();
            }
            if (tid < 8) toks[tid] = ri[tid];
            __syncthreads();
          }
          for (int b = 0; b < 8; ++b)
            xl[b * 260 + tid] = tok_emb[(size_t)toks[b] * 256 + tid] + pos_enc[t * 256 + tid];
          __syncthreads();
        } else {
          unsigned s = waitf(FL + FFPX(l - 1, bid & 7) * FSTR, 8u * (unsigned)(t + 1), &saltsh);
          int lp = l - 1, par = lp & 1;
          float u8[8];
          pull8p(u8, u + lp * 2048 + 0 * 256 + tid, u + lp * 2048 + 1 * 256 + tid,
                 u + lp * 2048 + 2 * 256 + tid, u + lp * 2048 + 3 * 256 + tid,
                 u + lp * 2048 + 4 * 256 + tid, u + lp * 2048 + 5 * 256 + tid,
                 u + lp * 2048 + 6 * 256 + tid, u + lp * 2048 + 7 * 256 + tid, s);
          float4 fA[8], fB[8];
          const float* fb = ffp + par * 16384;
          pull4x8(fA, fb + (0 * 256 + tid) * 8, fb + (1 * 256 + tid) * 8,
                  fb + (2 * 256 + tid) * 8, fb + (3 * 256 + tid) * 8, s);
          pull4x8(fB, fb + (4 * 256 + tid) * 8, fb + (5 * 256 + tid) * 8,
                  fb + (6 * 256 + tid) * 8, fb + (7 * 256 + tid) * 8, s);
          float g = ln_g[(lp * 3 + 2) * 256 + tid], bt = ln_b[(lp * 3 + 2) * 256 + tid];
          float f2b = ff2_b[lp * 256 + tid];
#pragma unroll
          for (int b = 0; b < 8; ++b) {
            float4 q0 = (b < 4) ? fA[2 * b] : fB[2 * (b - 4)];
            float4 q1 = (b < 4) ? fA[2 * b + 1] : fB[2 * (b - 4) + 1];
            float a = u8[b] + f2b + q0.x + q0.y + q0.z + q0.w + q1.x + q1.y + q1.z + q1.w;
            xl[b * 260 + tid] = block_ln256(a, tid, red8, g, bt);
          }
          __syncthreads();
        }
        // GEMV rows qi*32..+32
        int r = tid >> 3, b8 = tid & 7;
        int row = qi * 32 + r;
        float acc = sa_in_b[l * 768 + row];
        const float4* w4 = reinterpret_cast<const float4*>(sa_in_w + (size_t)(l * 768 + row) * 256);
        const float4* xv = reinterpret_cast<const float4*>(xl + b8 * 260);
#pragma unroll 8
        for (int k = 0; k < 64; ++k) {
          float4 wv = w4[k]; float4 xq = xv[k];
          acc += wv.x * xq.x + wv.y * xq.y + wv.z * xq.z + wv.w * xq.w;
        }
        if (row < 256) gst(qb + b8 * 256 + row, acc);
        else if (row < 512) gst(kb + b8 * 256 + (row - 256), acc);
        else gst(vb + b8 * 256 + (row - 512), acc);
        bump(FL + FQKV(l) * FSTR);
      }
      unsigned s4 = waitf(FL + FXF(bid & 7) * FSTR, 8u * (unsigned)(t + 1), &saltsh);
      fc_phase(bid, tid, t, s4, xf, fc_w, fc_b, out, pv, pi, xl, rv, ri);
      bump(FL + FFC(bid & 7) * FSTR);
    }
  } else if (bid < 64) {
    // ======= FFN role: slice s (256 neurons), transposed partial store =======
    int s = bid - 56;
    for (int t = 0; t < NSTEP; ++t) {
      for (int l = 0; l < 4; ++l) {
        unsigned sv = waitf(FL + FU(l) * FSTR, 8u * (unsigned)(t + 1), &saltsh);
        {
          float u8[8];
          pull8p(u8, u + l * 2048 + 0 * 256 + tid, u + l * 2048 + 1 * 256 + tid,
                 u + l * 2048 + 2 * 256 + tid, u + l * 2048 + 3 * 256 + tid,
                 u + l * 2048 + 4 * 256 + tid, u + l * 2048 + 5 * 256 + tid,
                 u + l * 2048 + 6 * 256 + tid, u + l * 2048 + 7 * 256 + tid, sv);
#pragma unroll
          for (int b = 0; b < 8; ++b) xl[b * 260 + tid] = u8[b];
        }
        __syncthreads();
        // ff1: neuron row s*256+tid for all 8 batches
        {
          int row = s * 256 + tid;
          float acc[8];
          float bb = ff1_b[l * 2048 + row];
#pragma unroll
          for (int b = 0; b < 8; ++b) acc[b] = bb;
          const float4* w4 = reinterpret_cast<const float4*>(ff1_w + (size_t)(l * 2048 + row) * 256);
          for (int k = 0; k < 64; ++k) {
            float4 wv = w4[k];
#pragma unroll
            for (int b = 0; b < 8; ++b) {
              const float4 xq = reinterpret_cast<const float4*>(xl + b * 260)[k];
              acc[b] += wv.x * xq.x + wv.y * xq.y + wv.z * xq.z + wv.w * xq.w;
            }
          }
#pragma unroll
          for (int b = 0; b < 8; ++b) h1l[tid * 9 + b] = fmaxf(acc[b], 0.f);
        }
        __syncthreads();
        // ff2 partial: out-dim tid, neurons s*256..+256
        {
          float facc[8] = {0, 0, 0, 0, 0, 0, 0, 0};
          const float* w2p = ff2_w + (size_t)(l * 256 + tid) * 2048 + s * 256;
          for (int n = 0; n < 256; ++n) {
            float wv = w2p[n];
#pragma unroll
            for (int b = 0; b < 8; ++b) facc[b] += wv * h1l[n * 9 + b];
          }
          int par = l & 1;
#pragma unroll
          for (int b = 0; b < 8; ++b)
            gst(ffp + par * 16384 + (b * 256 + tid) * 8 + s, facc[b]);
        }
        bump8(FL + FFPX(l, 0) * FSTR);
        __syncthreads();
      }
      unsigned s4 = waitf(FL + FXF(bid & 7) * FSTR, 8u * (unsigned)(t + 1), &saltsh);
      fc_phase(bid, tid, t, s4, xf, fc_w, fc_b, out, pv, pi, xl, rv, ri);
      bump(FL + FFC(bid & 7) * FSTR);
    }
  } else {
    // ======= fc-only role =======
    for (int t = 0; t < NSTEP; ++t) {
      unsigned s4 = waitf(FL + FXF(bid & 7) * FSTR, 8u * (unsigned)(t + 1), &saltsh);
      fc_phase(bid, tid, t, s4, xf, fc_w, fc_b, out, pv, pi, xl, rv, ri);
      bump(FL + FFC(bid & 7) * FSTR);
    }
  }
}

// ================= fallback path (round-1, proven) =================
__device__ __forceinline__ float block_ln(float v, int tid, float* red, float* red2,
                                          float g, float bta) {
  red[tid] = v; red2[tid] = v * v;
  __syncthreads();
  for (int off = 128; off > 0; off >>= 1) {
    if (tid < off) { red[tid] += red[tid + off]; red2[tid] += red2[tid + off]; }
    __syncthreads();
  }
  float m = red[0] * (1.0f / 256.0f);
  float var = red2[0] * (1.0f / 256.0f) - m * m;
  float rs = rsqrtf(var + LNEPS);
  float y = (v - m) * rs * g + bta;
  __syncthreads();
  return y;
}

__global__ __launch_bounds__(256) void k_mem(const float* __restrict__ emb,
                                             const float* __restrict__ w,
                                             const float* __restrict__ bias,
                                             float* __restrict__ mem) {
  __shared__ float el[1536];
  __shared__ float red[256];
  int b = blockIdx.x >> 3, tile = blockIdx.x & 7, tid = threadIdx.x;
  for (int k = tid; k < 1536; k += 256) el[k] = emb[b * 1536 + k];
  __syncthreads();
  int r = tid >> 3, g = tid & 7;
  int row = tile * 32 + r;
  float acc = 0.f;
  const float* wr = w + row * 1536;
  for (int c = g * 192; c < g * 192 + 192; ++c) acc += wr[c] * el[c];
  red[tid] = acc;
  __syncthreads();
  for (int off = 4; off >= 1; off >>= 1) {
    if (g < off) red[tid] += red[tid + off];
    __syncthreads();
  }
  if (g == 0) mem[b * 256 + row] = red[tid] + bias[row];
}

__global__ __launch_bounds__(256) void k_ca(const float* __restrict__ mem,
                                            const float* __restrict__ iw,
                                            const float* __restrict__ ib,
                                            const float* __restrict__ ow,
                                            const float* __restrict__ ob,
                                            float* __restrict__ ca) {
  __shared__ float ml[256], vl[256];
  int l = blockIdx.x >> 3, b = blockIdx.x & 7, tid = threadIdx.x;
  ml[tid] = mem[b * 256 + tid];
  __syncthreads();
  float acc = ib[l * 768 + 512 + tid];
  const float* wr = iw + (size_t)(l * 768 + 512 + tid) * 256;
  for (int c = 0; c < 256; ++c) acc += wr[c] * ml[c];
  vl[tid] = acc;
  __syncthreads();
  float acc2 = ob[l * 256 + tid];
  const float* wr2 = ow + (size_t)(l * 256 + tid) * 256;
  for (int c = 0; c < 256; ++c) acc2 += wr2[c] * vl[c];
  ca[(l * 8 + b) * 256 + tid] = acc2;
}

__global__ void k_tok_init(int* __restrict__ tok) {
  if (threadIdx.x < 8) tok[threadIdx.x * 64] = BOSTOK;
}

__global__ __launch_bounds__(256) void k_embed(const int* __restrict__ tok,
                                               const float* __restrict__ te,
                                               const float* __restrict__ pe,
                                               float* __restrict__ x, int t) {
  int tid = threadIdx.x;
  for (int b = 0; b < 8; ++b) {
    int tk = tok[b * 64 + t];
    x[b * 256 + tid] = te[(size_t)tk * 256 + tid] + pe[t * 256 + tid];
  }
}

__global__ __launch_bounds__(256) void k_qkv(const float* __restrict__ x,
                                             const float* __restrict__ w,
                                             const float* __restrict__ bias,
                                             float* __restrict__ q,
                                             float* __restrict__ kc,
                                             float* __restrict__ vc, int l, int t) {
  __shared__ float xl[8 * 260];
  int tid = threadIdx.x;
  for (int k = 0; k < 8; ++k) {
    int idx = tid + k * 256;
    xl[(idx >> 8) * 260 + (idx & 255)] = x[idx];
  }
  __syncthreads();
  int r = tid >> 3, b = tid & 7;
  int row = blockIdx.x * 32 + r;
  float acc = bias[l * 768 + row];
  const float4* w4 = reinterpret_cast<const float4*>(w + (size_t)(l * 768 + row) * 256);
  const float4* xv = reinterpret_cast<const float4*>(xl + b * 260);
#pragma unroll 8
  for (int k = 0; k < 64; ++k) {
    float4 wv = w4[k]; float4 xq = xv[k];
    acc += wv.x * xq.x + wv.y * xq.y + wv.z * xq.z + wv.w * xq.w;
  }
  if (row < 256) {
    q[b * 256 + row] = acc;
  } else if (row < 512) {
    int h = (row - 256) >> 5, d = (row - 256) & 31;
    kc[(((l * 8 + b) * 8 + h) * 50 + t) * 32 + d] = acc;
  } else {
    int h = (row - 512) >> 5, d = (row - 512) & 31;
    vc[(((l * 8 + b) * 8 + h) * 50 + t) * 32 + d] = acc;
  }
}

__global__ __launch_bounds__(256) void k_attn(const float* __restrict__ q,
                                              float* __restrict__ x,
                                              const float* __restrict__ kc,
                                              const float* __restrict__ vc,
                                              const float* __restrict__ ow,
                                              const float* __restrict__ ob,
                                              const float* __restrict__ lg,
                                              const float* __restrict__ lb,
                                              const float* __restrict__ ca, int l, int t) {
  __shared__ float ql[256], ol[256], sc[64], red[256], red2[256];
  __shared__ float ssum;
  int b = blockIdx.x, tid = threadIdx.x;
  float xres = x[b * 256 + tid];
  ql[tid] = q[b * 256 + tid];
  __syncthreads();
  for (int h = 0; h < 8; ++h) {
    const float* kb = kc + (size_t)(((l * 8 + b) * 8 + h) * 50) * 32;
    if (tid <= t) {
      float s = 0.f;
      const float* kr = kb + tid * 32;
#pragma unroll
      for (int d = 0; d < 32; ++d) s += ql[h * 32 + d] * kr[d];
      sc[tid] = s * 0.17677669529663687f;
    }
    __syncthreads();
    if (tid < 64) {
      float v = (tid <= t) ? sc[tid] : -1e30f;
      float mx = v;
      for (int m = 32; m >= 1; m >>= 1) mx = fmaxf(mx, __shfl_xor(mx, m));
      float e = (tid <= t) ? expf(sc[tid] - mx) : 0.f;
      sc[tid] = e;
      float sm = e;
      for (int m = 32; m >= 1; m >>= 1) sm += __shfl_xor(sm, m);
      if (tid == 0) ssum = sm;
    }
    __syncthreads();
    if (tid < 32) {
      const float* vb = vc + (size_t)(((l * 8 + b) * 8 + h) * 50) * 32 + tid;
      float acc = 0.f;
      for (int j = 0; j <= t; ++j) acc += sc[j] * vb[j * 32];
      ol[h * 32 + tid] = acc / ssum;
    }
    __syncthreads();
  }
  float acc = ob[l * 256 + tid];
  const float4* w4 = reinterpret_cast<const float4*>(ow + (size_t)(l * 256 + tid) * 256);
#pragma unroll 4
  for (int k = 0; k < 64; ++k) {
    float4 wv = w4[k];
    acc += wv.x * ol[4 * k] + wv.y * ol[4 * k + 1] + wv.z * ol[4 * k + 2] + wv.w * ol[4 * k + 3];
  }
  acc += xres;
  float y = block_ln(acc, tid, red, red2, lg[(l * 3 + 0) * 256 + tid], lb[(l * 3 + 0) * 256 + tid]);
  float acc2 = y + ca[(l * 8 + b) * 256 + tid];
  float y2 = block_ln(acc2, tid, red, red2, lg[(l * 3 + 1) * 256 + tid], lb[(l * 3 + 1) * 256 + tid]);
  x[b * 256 + tid] = y2;
}

__global__ __launch_bounds__(256) void k_ffn(const float* __restrict__ x,
                                             const float* __restrict__ w1,
                                             const float* __restrict__ b1,
                                             const float* __restrict__ w2,
                                             float* __restrict__ ffp, int l) {
  __shared__ float xl[8 * 260];
  __shared__ float h1l[64 * 9];
  int tid = threadIdx.x, s = blockIdx.x;
  for (int k = 0; k < 8; ++k) {
    int idx = tid + k * 256;
    xl[(idx >> 8) * 260 + (idx & 255)] = x[idx];
  }
  __syncthreads();
  int n0 = tid >> 3, b = tid & 7;
#pragma unroll
  for (int i = 0; i < 2; ++i) {
    int nn = n0 + i * 32, row = s * 64 + nn;
    float acc = b1[l * 2048 + row];
    const float4* w4 = reinterpret_cast<const float4*>(w1 + (size_t)(l * 2048 + row) * 256);
    const float4* xv = reinterpret_cast<const float4*>(xl + b * 260);
    for (int k = 0; k < 64; ++k) {
      float4 wv = w4[k]; float4 xq = xv[k];
      acc += wv.x * xq.x + wv.y * xq.y + wv.z * xq.z + wv.w * xq.w;
    }
    h1l[nn * 9 + b] = fmaxf(acc, 0.f);
  }
  __syncthreads();
  int row = tid;
  float acc[8] = {0, 0, 0, 0, 0, 0, 0, 0};
  const float* w2p = w2 + (size_t)(l * 256 + row) * 2048 + s * 64;
  for (int n = 0; n < 64; ++n) {
    float wv = w2p[n];
#pragma unroll
    for (int b2 = 0; b2 < 8; ++b2) acc[b2] += wv * h1l[n * 9 + b2];
  }
  for (int b2 = 0; b2 < 8; ++b2) ffp[(s * 8 + b2) * 256 + row] = acc[b2];
}

__global__ __launch_bounds__(256) void k_ffred(float* __restrict__ x,
                                               const float* __restrict__ ffp,
                                               const float* __restrict__ b2,
                                               const float* __restrict__ lg,
                                               const float* __restrict__ lb, int l) {
  __shared__ float red[256], red2[256];
  int b = blockIdx.x, tid = threadIdx.x;
  float acc = b2[l * 256 + tid] + x[b * 256 + tid];
  for (int s = 0; s < 32; ++s) acc += ffp[(s * 8 + b) * 256 + tid];
  float y = block_ln(acc, tid, red, red2, lg[(l * 3 + 2) * 256 + tid], lb[(l * 3 + 2) * 256 + tid]);
  x[b * 256 + tid] = y;
}

__global__ __launch_bounds__(256) void k_fc(const float* __restrict__ h,
                                            const float* __restrict__ w,
                                            const float* __restrict__ bias,
                                            float* __restrict__ out,
                                            float* __restrict__ pv,
                                            int* __restrict__ pi, int t) {
  __shared__ float hl[8 * 260];
  __shared__ float rv[256];
  __shared__ int ri[256];
  int tid = threadIdx.x, wg = blockIdx.x;
  for (int k = 0; k < 8; ++k) {
    int idx = tid + k * 256;
    hl[(idx >> 8) * 260 + (idx & 255)] = h[idx];
  }
  __syncthreads();
  int r = tid >> 3, b = tid & 7;
  float bv = -3e38f;
  int bi = 2147483647;
  for (int i = 0; i < 2; ++i) {
    int row = wg * 64 + i * 32 + r;
    if (row < NV) {
      float acc = bias[row];
      const float4* w4 = reinterpret_cast<const float4*>(w + (size_t)row * 256);
      const float4* xv = reinterpret_cast<const float4*>(hl + b * 260);
      for (int k = 0; k < 64; ++k) {
        float4 wv = w4[k]; float4 xq = xv[k];
        acc += wv.x * xq.x + wv.y * xq.y + wv.z * xq.z + wv.w * xq.w;
      }
      out[(size_t)(b * 49 + t) * NV + row] = acc;
      if (acc > bv || (acc == bv && row < bi)) { bv = acc; bi = row; }
    }
  }
  rv[tid] = bv; ri[tid] = bi;
  __syncthreads();
  for (int off = 128; off >= 8; off >>= 1) {
    if (tid < off) {
      float v = rv[tid + off]; int id = ri[tid + off];
      if (v > rv[tid] || (v == rv[tid] && id < ri[tid])) { rv[tid] = v; ri[tid] = id; }
    }
    __syncthreads();
  }
  if (tid < 8) { pv[wg * 8 + tid] = rv[tid]; pi[wg * 8 + tid] = ri[tid]; }
}

__global__ __launch_bounds__(256) void k_amax(const float* __restrict__ pv,
                                              const int* __restrict__ pi,
                                              int* __restrict__ tok, int t) {
  __shared__ float rv[256];
  __shared__ int ri[256];
  int tid = threadIdx.x, b = tid & 7, i0 = tid >> 3;
  float bv = -3e38f;
  int bi = 2147483647;
  for (int p = i0; p < FCT; p += 32) {
    float v = pv[p * 8 + b]; int id = pi[p * 8 + b];
    if (v > bv || (v == bv && id < bi)) { bv = v; bi = id; }
  }
  rv[tid] = bv; ri[tid] = bi;
  __syncthreads();
  for (int off = 128; off >= 8; off >>= 1) {
    if (tid < off) {
      float v = rv[tid + off]; int id = ri[tid + off];
      if (v > rv[tid] || (v == rv[tid] && id < ri[tid])) { rv[tid] = v; ri[tid] = id; }
    }
    __syncthreads();
  }
  if (tid < 8) tok[tid * 64 + t + 1] = ri[tid];
}

extern "C" void kernel_launch(void* const* d_in, const int* in_sizes, int n_in,
                              void* d_out, int out_size, void* d_ws, size_t ws_size,
                              hipStream_t stream) {
  (void)in_sizes; (void)n_in; (void)out_size; (void)ws_size;
  const float* embedding = (const float*)d_in[0];
  const float* w_proj   = (const float*)d_in[1];
  const float* b_proj   = (const float*)d_in[2];
  const float* tok_emb  = (const float*)d_in[3];
  const float* pos_enc  = (const float*)d_in[4];
  const float* sa_in_w  = (const float*)d_in[5];
  const float* sa_in_b  = (const float*)d_in[6];
  const float* sa_out_w = (const float*)d_in[7];
  const float* sa_out_b = (const float*)d_in[8];
  const float* ca_in_w  = (const float*)d_in[9];
  const float* ca_in_b  = (const float*)d_in[10];
  const float* ca_out_w = (const float*)d_in[11];
  const float* ca_out_b = (const float*)d_in[12];
  const float* ff1_w    = (const float*)d_in[13];
  const float* ff1_b    = (const float*)d_in[14];
  const float* ff2_w    = (const float*)d_in[15];
  const float* ff2_b    = (const float*)d_in[16];
  const float* ln_g     = (const float*)d_in[17];
  const float* ln_b     = (const float*)d_in[18];
  const float* fc_w     = (const float*)d_in[19];
  const float* fc_b     = (const float*)d_in[20];
  float* out = (float*)d_out;
  float* wsf = (float*)d_ws;
  int*   wsi = (int*)d_ws;

  int dev = 0;
  (void)hipGetDevice(&dev);
  int coopAttr = 0;
  (void)hipDeviceGetAttribute(&coopAttr, hipDeviceAttributeCooperativeLaunch, dev);
  int ncu = 0;
  (void)hipDeviceGetAttribute(&ncu, hipDeviceAttributeMultiprocessorCount, dev);
  (void)hipFuncSetAttribute(reinterpret_cast<const void*>(k_flow4),
                            hipFuncAttributeMaxDynamicSharedMemorySize, DYN_LDS_BYTES);
  int maxb = 0;
  hipError_t oe = hipOccupancyMaxActiveBlocksPerMultiprocessor(&maxb, k_flow4, 256, DYN_LDS_BYTES);

  bool coop_ok = (coopAttr != 0) && (oe == hipSuccess) && ((long)maxb * (long)ncu >= NBLK);

  if (coop_ok) {
    (void)hipMemsetAsync(d_ws, 0, 16384, stream);  // zero flag lines
    void* args[] = {
        (void*)&embedding, (void*)&w_proj, (void*)&b_proj, (void*)&tok_emb, (void*)&pos_enc,
        (void*)&sa_in_w, (void*)&sa_in_b, (void*)&sa_out_w, (void*)&sa_out_b,
        (void*)&ca_in_w, (void*)&ca_in_b, (void*)&ca_out_w, (void*)&ca_out_b,
        (void*)&ff1_w, (void*)&ff1_b, (void*)&ff2_w, (void*)&ff2_b,
        (void*)&ln_g, (void*)&ln_b, (void*)&fc_w, (void*)&fc_b,
        (void*)&out, (void*)&wsf, (void*)&wsi};
    hipError_t le = hipLaunchCooperativeKernel((void*)k_flow4, dim3(NBLK), dim3(256),
                                               args, DYN_LDS_BYTES, stream);
    if (le != hipSuccess) coop_ok = false;
  }

  if (!coop_ok) {
    float* mem = wsf + WS_MEM;
    float* ca  = wsf + WS_CA;
    float* x   = wsf + WS_X;
    float* q   = wsf + WS_Q;
    float* ffp = wsf + WS_FFP;
    float* kc  = wsf + WS_KC;
    float* vc  = wsf + WS_VC;
    float* pv  = wsf + WS_PV;
    int*   pi  = wsi + WS_PI;
    int*   tok = wsi + WS_TOK;

    k_mem<<<64, 256, 0, stream>>>(embedding, w_proj, b_proj, mem);
    k_ca<<<32, 256, 0, stream>>>(mem, ca_in_w, ca_in_b, ca_out_w, ca_out_b, ca);
    k_tok_init<<<1, 64, 0, stream>>>(tok);

    for (int t = 0; t < NSTEP; ++t) {
      k_embed<<<1, 256, 0, stream>>>(tok, tok_emb, pos_enc, x, t);
      for (int l = 0; l < 4; ++l) {
        k_qkv<<<24, 256, 0, stream>>>(x, sa_in_w, sa_in_b, q, kc, vc, l, t);
        k_attn<<<8, 256, 0, stream>>>(q, x, kc, vc, sa_out_w, sa_out_b, ln_g, ln_b, ca, l, t);
        k_ffn<<<32, 256, 0, stream>>>(x, ff1_w, ff1_b, ff2_w, ffp, l);
        k_ffred<<<8, 256, 0, stream>>>(x, ffp, ff2_b, ln_g, ln_b, l);
      }
      k_fc<<<FCT, 256, 0, stream>>>(x, fc_w, fc_b, out, pv, pi, t);
      k_amax<<<1, 256, 0, stream>>>(pv, pi, tok, t);
    }
  }
}

// Round 9
// 10714.751 us; speedup vs baseline: 1.2723x; 1.2720x over previous
//
#include <hip/hip_runtime.h>

#define NV 50257
#define BOSTOK 50256
#define LNEPS 1e-5f
#define NSTEP 49
#define NBLK 256
#define RPB 197
#define DYN_LDS_BYTES ((256 * 52 + 50 * 256) * 4)
#define FSTR 64

// flag line indices (each its own 256B line)
#define FQKV(l)   (0 + (l))              // +24/step
#define FU(l)     (4 + (l))              // +8/step
#define FFPX(l,j) (8 + (l) * 8 + (j))    // +8/step per replica
#define FXF(j)    (40 + (j))             // +8/step per replica
#define FFC(j)    (48 + (j))             // +32/step per replica
#define FMEMF     56
#define FCAF      57

// float offsets in d_ws; flags occupy words 0..4095
#define WS4_MEM 4096
#define WS4_CA  6144
#define WS4_XF  14336
#define WS4_Q   16384
#define WS4_K   18432
#define WS4_V   20480
#define WS4_U   22528    // [l][b][256] -> 4*2048
#define WS4_FFP 30720    // [par][b*256+tid][8] -> 2*16384
#define WS4_PV  63488
#define WS4_PI  65536

// ---------- coherent scalar helpers ----------
__device__ __forceinline__ float gld(const float* p) {
  return __hip_atomic_load(const_cast<float*>(p), __ATOMIC_RELAXED, __HIP_MEMORY_SCOPE_AGENT);
}
__device__ __forceinline__ void gst(float* p, float v) {
  __hip_atomic_store(p, v, __ATOMIC_RELAXED, __HIP_MEMORY_SCOPE_AGENT);
}
__device__ __forceinline__ void gsti(int* p, int v) {
  __hip_atomic_store(p, v, __ATOMIC_RELAXED, __HIP_MEMORY_SCOPE_AGENT);
}
__device__ __forceinline__ unsigned fld(unsigned* p) {
  return __hip_atomic_load(p, __ATOMIC_RELAXED, __HIP_MEMORY_SCOPE_AGENT);
}
__device__ __forceinline__ void bump(unsigned* f) {
  asm volatile("s_waitcnt vmcnt(0)" ::: "memory");
  __syncthreads();
  if (threadIdx.x == 0)
    __hip_atomic_fetch_add(f, 1u, __ATOMIC_RELAXED, __HIP_MEMORY_SCOPE_AGENT);
}
__device__ __forceinline__ void bump8(unsigned* f) {
  asm volatile("s_waitcnt vmcnt(0)" ::: "memory");
  __syncthreads();
  if (threadIdx.x == 0)
    for (int j = 0; j < 8; ++j)
      __hip_atomic_fetch_add(f + j * FSTR, 1u, __ATOMIC_RELAXED, __HIP_MEMORY_SCOPE_AGENT);
}
__device__ __forceinline__ unsigned waitf(unsigned* f, unsigned tgt, unsigned* sh) {
  if (threadIdx.x == 0) {
    unsigned v = fld(f);
    while (v < tgt) { __builtin_amdgcn_s_sleep(1); v = fld(f); }
    *sh = v;
  }
  __syncthreads();
  return *sh;
}
__device__ __forceinline__ unsigned wait_fcsum(unsigned* FL, unsigned tgt, unsigned* sh) {
  if (threadIdx.x == 0) {
    unsigned s;
    for (;;) {
      s = 0;
      for (int j = 0; j < 8; ++j) s += fld(FL + (48 + j) * FSTR);
      if (s >= tgt) break;
      __builtin_amdgcn_s_sleep(1);
    }
    *sh = s;
  }
  __syncthreads();
  return *sh;
}

// ---------- batched LLC pulls (issue N, wait once) ----------
__device__ __forceinline__ void pull2p(float* x, float* y,
    const float* p0, const float* p1, unsigned salt) {
  asm("global_load_dword %0, %2, off sc0 sc1\n\t"
      "global_load_dword %1, %3, off sc0 sc1\n\t"
      "s_waitcnt vmcnt(0)"
      : "=&v"(*x), "=&v"(*y)
      : "v"(p0), "v"(p1), "v"(salt));
}
__device__ __forceinline__ void pull3p(float* x, float* y, float* z,
    const float* p0, const float* p1, const float* p2, unsigned salt) {
  asm("global_load_dword %0, %3, off sc0 sc1\n\t"
      "global_load_dword %1, %4, off sc0 sc1\n\t"
      "global_load_dword %2, %5, off sc0 sc1\n\t"
      "s_waitcnt vmcnt(0)"
      : "=&v"(*x), "=&v"(*y), "=&v"(*z)
      : "v"(p0), "v"(p1), "v"(p2), "v"(salt));
}
__device__ __forceinline__ void pull8p(float r[8],
    const float* p0, const float* p1, const float* p2, const float* p3,
    const float* p4, const float* p5, const float* p6, const float* p7, unsigned salt) {
  float a0, a1, a2, a3, a4, a5, a6, a7;
  asm("global_load_dword %0, %8, off sc0 sc1\n\t"
      "global_load_dword %1, %9, off sc0 sc1\n\t"
      "global_load_dword %2, %10, off sc0 sc1\n\t"
      "global_load_dword %3, %11, off sc0 sc1\n\t"
      "global_load_dword %4, %12, off sc0 sc1\n\t"
      "global_load_dword %5, %13, off sc0 sc1\n\t"
      "global_load_dword %6, %14, off sc0 sc1\n\t"
      "global_load_dword %7, %15, off sc0 sc1\n\t"
      "s_waitcnt vmcnt(0)"
      : "=&v"(a0), "=&v"(a1), "=&v"(a2), "=&v"(a3),
        "=&v"(a4), "=&v"(a5), "=&v"(a6), "=&v"(a7)
      : "v"(p0), "v"(p1), "v"(p2), "v"(p3), "v"(p4), "v"(p5), "v"(p6), "v"(p7), "v"(salt));
  r[0] = a0; r[1] = a1; r[2] = a2; r[3] = a3;
  r[4] = a4; r[5] = a5; r[6] = a6; r[7] = a7;
}
// u + 8 contiguous ffp floats (2x dwordx4) for one row
__device__ __forceinline__ void pull1_2q(float* u, float4* f0, float4* f1,
    const float* pu, const float* pf, unsigned salt) {
  asm("global_load_dword %0, %3, off sc0 sc1\n\t"
      "global_load_dwordx4 %1, %4, off sc0 sc1\n\t"
      "global_load_dwordx4 %2, %4, off offset:16 sc0 sc1\n\t"
      "s_waitcnt vmcnt(0)"
      : "=&v"(*u), "=&v"(*f0), "=&v"(*f1)
      : "v"(pu), "v"(pf), "v"(salt));
}
// 4 rows x 8 floats (2 dwordx4 each)
__device__ __forceinline__ void pull4x8(float4 r[8],
    const float* p0, const float* p1, const float* p2, const float* p3, unsigned salt) {
  float4 a0, a1, a2, a3, a4, a5, a6, a7;
  asm("global_load_dwordx4 %0, %8, off sc0 sc1\n\t"
      "global_load_dwordx4 %1, %8, off offset:16 sc0 sc1\n\t"
      "global_load_dwordx4 %2, %9, off sc0 sc1\n\t"
      "global_load_dwordx4 %3, %9, off offset:16 sc0 sc1\n\t"
      "global_load_dwordx4 %4, %10, off sc0 sc1\n\t"
      "global_load_dwordx4 %5, %10, off offset:16 sc0 sc1\n\t"
      "global_load_dwordx4 %6, %11, off sc0 sc1\n\t"
      "global_load_dwordx4 %7, %11, off offset:16 sc0 sc1\n\t"
      "s_waitcnt vmcnt(0)"
      : "=&v"(a0), "=&v"(a1), "=&v"(a2), "=&v"(a3),
        "=&v"(a4), "=&v"(a5), "=&v"(a6), "=&v"(a7)
      : "v"(p0), "v"(p1), "v"(p2), "v"(p3), "v"(salt));
  r[0] = a0; r[1] = a1; r[2] = a2; r[3] = a3;
  r[4] = a4; r[5] = a5; r[6] = a6; r[7] = a7;
}

__device__ __forceinline__ float block_ln256(float v, int tid, float* red8, float g, float bta) {
  float s = v, s2 = v * v;
#pragma unroll
  for (int m = 32; m >= 1; m >>= 1) { s += __shfl_xor(s, m); s2 += __shfl_xor(s2, m); }
  int w = tid >> 6;
  __syncthreads();
  if ((tid & 63) == 0) { red8[w] = s; red8[4 + w] = s2; }
  __syncthreads();
  s = red8[0] + red8[1] + red8[2] + red8[3];
  s2 = red8[4] + red8[5] + red8[6] + red8[7];
  float mn = s * (1.0f / 256.0f);
  float var = s2 * (1.0f / 256.0f) - mn * mn;
  float rs = rsqrtf(var + LNEPS);
  return (v - mn) * rs * g + bta;
}

// fc GEMV + per-block argmax partial
__device__ __forceinline__ void fc_phase(int bid, int tid, int t, unsigned salt,
                                         const float* xf, const float* fc_w,
                                         const float* fc_b, float* out,
                                         float* pv, int* pi,
                                         float* xl, float* rv, int* ri) {
  {
    float xv8[8];
    pull8p(xv8, xf + 0 * 256 + tid, xf + 1 * 256 + tid, xf + 2 * 256 + tid, xf + 3 * 256 + tid,
           xf + 4 * 256 + tid, xf + 5 * 256 + tid, xf + 6 * 256 + tid, xf + 7 * 256 + tid, salt);
#pragma unroll
    for (int b = 0; b < 8; ++b) xl[b * 260 + tid] = xv8[b];
  }
  __syncthreads();
  int r = tid >> 3, b = tid & 7;
  float bv = -3e38f; int bi = 2147483647;
  int base = bid * RPB;
  for (int i = 0; i < 7; ++i) {
    int rr = i * 32 + r, row = base + rr;
    if (rr < RPB && row < NV) {
      float acc = fc_b[row];
      const float4* w4 = reinterpret_cast<const float4*>(fc_w + (size_t)row * 256);
      const float4* xv = reinterpret_cast<const float4*>(xl + b * 260);
      for (int k = 0; k < 64; ++k) {
        float4 wv = w4[k]; float4 xq = xv[k];
        acc += wv.x * xq.x + wv.y * xq.y + wv.z * xq.z + wv.w * xq.w;
      }
      out[(size_t)(b * 49 + t) * NV + row] = acc;
      if (acc > bv || (acc == bv && row < bi)) { bv = acc; bi = row; }
    }
  }
  rv[tid] = bv; ri[tid] = bi;
  __syncthreads();
  for (int off = 128; off >= 8; off >>= 1) {
    if (tid < off) {
      float v = rv[tid + off]; int id = ri[tid + off];
      if (v > rv[tid] || (v == rv[tid] && id < ri[tid])) { rv[tid] = v; ri[tid] = id; }
    }
    __syncthreads();
  }
  if (tid < 8) { gst(pv + bid * 8 + tid, rv[tid]); gsti(pi + bid * 8 + tid, ri[tid]); }
}

// ================= single-dispatch dataflow kernel v4 (proven round-7 correct) =================
__global__ __launch_bounds__(256) void k_flow4(
    const float* __restrict__ emb, const float* __restrict__ w_proj, const float* __restrict__ b_proj,
    const float* __restrict__ tok_emb, const float* __restrict__ pos_enc,
    const float* __restrict__ sa_in_w, const float* __restrict__ sa_in_b,
    const float* __restrict__ sa_out_w, const float* __restrict__ sa_out_b,
    const float* __restrict__ ca_in_w, const float* __restrict__ ca_in_b,
    const float* __restrict__ ca_out_w, const float* __restrict__ ca_out_b,
    const float* __restrict__ ff1_w, const float* __restrict__ ff1_b,
    const float* __restrict__ ff2_w, const float* __restrict__ ff2_b,
    const float* __restrict__ ln_g, const float* __restrict__ ln_b,
    const float* __restrict__ fc_w, const float* __restrict__ fc_b,
    float* __restrict__ out, float* __restrict__ wsf, int* __restrict__ wsi) {
  extern __shared__ float dynlds[];   // ATTN blocks: K [256][52] d-major + V [50][256]
  const int bid = blockIdx.x, tid = threadIdx.x;

  unsigned* FL = (unsigned*)wsf;
  float* mem = wsf + WS4_MEM;
  float* ca  = wsf + WS4_CA;
  float* xf  = wsf + WS4_XF;
  float* qb  = wsf + WS4_Q;
  float* kb  = wsf + WS4_K;
  float* vb  = wsf + WS4_V;
  float* u   = wsf + WS4_U;
  float* ffp = wsf + WS4_FFP;
  float* pv  = wsf + WS4_PV;
  int*   pi  = wsi + WS4_PI;

  __shared__ float xl[8 * 260];
  __shared__ float h1l[256 * 9];
  __shared__ float ql[256], ol[256], ph[8 * 64];
  __shared__ float red8[8];
  __shared__ float rv[256];
  __shared__ int   ri[256];
  __shared__ int   toks[8];
  __shared__ unsigned saltsh;
  __shared__ float el[1536];

  // ---- init 1: mem = embedding @ w_proj.T + b_proj (blocks 0..63)
  if (bid < 64) {
    int b = bid >> 3, tile = bid & 7;
    for (int k = tid; k < 1536; k += 256) el[k] = emb[b * 1536 + k];
    __syncthreads();
    int r = tid >> 3, g = tid & 7;
    int row = tile * 32 + r;
    float acc = 0.f;
    const float* wr = w_proj + (size_t)row * 1536;
    for (int c = g * 192; c < g * 192 + 192; ++c) acc += wr[c] * el[c];
    rv[tid] = acc;
    __syncthreads();
    for (int off = 4; off >= 1; off >>= 1) {
      if (g < off) rv[tid] += rv[tid + off];
      __syncthreads();
    }
    if (g == 0) gst(mem + b * 256 + row, rv[tid] + b_proj[row]);
    bump(FL + FMEMF * FSTR);
  }
  // ---- init 2: cross-attn constant (memory len 1 => attn == V_mem) (blocks 64..95)
  if (bid >= 64 && bid < 96) {
    unsigned s0 = waitf(FL + FMEMF * FSTR, 64u, &saltsh);
    int l = (bid - 64) >> 3, b = (bid - 64) & 7;
    ql[tid] = gld(mem + b * 256 + tid) + 0.f * (float)(s0 & 0);
    __syncthreads();
    float acc = ca_in_b[l * 768 + 512 + tid];
    const float* wr = ca_in_w + (size_t)(l * 768 + 512 + tid) * 256;
    for (int c = 0; c < 256; ++c) acc += wr[c] * ql[c];
    ol[tid] = acc;
    __syncthreads();
    float acc2 = ca_out_b[l * 256 + tid];
    const float* wr2 = ca_out_w + (size_t)(l * 256 + tid) * 256;
    for (int c = 0; c < 256; ++c) acc2 += wr2[c] * ol[c];
    gst(ca + (l * 8 + b) * 256 + tid, acc2);
    bump(FL + FCAF * FSTR);
  }

  if (bid < 32) {
    // ======= ATTN role: (myl,myb). front-LN (redundant) + attention + proj + LNs =======
    int myl = bid >> 3, myb = bid & 7;
    float* Klds = dynlds;
    float* Vlds = dynlds + 256 * 52;
    unsigned sc = waitf(FL + FCAF * FSTR, 32u, &saltsh);
    float caval = gld(ca + ((myl * 8 + myb) * 256 + (int)(sc & 0)) + tid);  // cached all steps
    for (int t = 0; t < NSTEP; ++t) {
      float xres;
      if (myl == 0) {
        if (t > 0) {
          unsigned s = wait_fcsum(FL, 256u * (unsigned)t, &saltsh);
          float pvv, piv;
          pull2p(&pvv, &piv, pv + tid * 8 + myb, (const float*)(pi + tid * 8 + myb), s);
          rv[tid] = pvv; ri[tid] = __float_as_int(piv);
          __syncthreads();
          for (int off = 128; off >= 1; off >>= 1) {
            if (tid < off) {
              float v = rv[tid + off]; int id = ri[tid + off];
              if (v > rv[tid] || (v == rv[tid] && id < ri[tid])) { rv[tid] = v; ri[tid] = id; }
            }
            __syncthreads();
          }
          if (tid == 0) toks[0] = ri[0];
          __syncthreads();
        } else {
          if (tid == 0) toks[0] = BOSTOK;
          __syncthreads();
        }
        xres = tok_emb[(size_t)toks[0] * 256 + tid] + pos_enc[t * 256 + tid];
      } else {
        unsigned s = waitf(FL + FFPX(myl - 1, bid & 7) * FSTR, 8u * (unsigned)(t + 1), &saltsh);
        float uv; float4 f0, f1;
        int par = (myl - 1) & 1;
        pull1_2q(&uv, &f0, &f1, u + (myl - 1) * 2048 + myb * 256 + tid,
                 ffp + par * 16384 + (myb * 256 + tid) * 8, s);
        float a = uv + ff2_b[(myl - 1) * 256 + tid]
                + f0.x + f0.y + f0.z + f0.w + f1.x + f1.y + f1.z + f1.w;
        xres = block_ln256(a, tid, red8, ln_g[((myl - 1) * 3 + 2) * 256 + tid],
                           ln_b[((myl - 1) * 3 + 2) * 256 + tid]);
      }
      // wait qkv, pull q/k/v for own batch
      unsigned s2 = waitf(FL + FQKV(myl) * FSTR, 24u * (unsigned)(t + 1), &saltsh);
      float qv, kv, vv;
      pull3p(&qv, &kv, &vv, qb + myb * 256 + tid, kb + myb * 256 + tid, vb + myb * 256 + tid, s2);
      ql[tid] = qv;
      Klds[tid * 52 + t] = kv;
      Vlds[t * 256 + tid] = vv;
      __syncthreads();
      int h = tid >> 5, j0 = tid & 31;
      const float* qh = ql + h * 32;
      float s0v = -3e38f, s1v = -3e38f;
      if (j0 <= t) {
        float d0 = 0.f;
#pragma unroll
        for (int d = 0; d < 32; ++d) d0 += qh[d] * Klds[(h * 32 + d) * 52 + j0];
        s0v = d0 * 0.17677669529663687f;
      }
      if (j0 + 32 <= t) {
        float d1 = 0.f;
#pragma unroll
        for (int d = 0; d < 32; ++d) d1 += qh[d] * Klds[(h * 32 + d) * 52 + j0 + 32];
        s1v = d1 * 0.17677669529663687f;
      }
      float mx = fmaxf(s0v, s1v);
      for (int m = 16; m >= 1; m >>= 1) mx = fmaxf(mx, __shfl_xor(mx, m, 32));
      float e0 = (j0 <= t) ? expf(s0v - mx) : 0.f;
      float e1 = (j0 + 32 <= t) ? expf(s1v - mx) : 0.f;
      float sm = e0 + e1;
      for (int m = 16; m >= 1; m >>= 1) sm += __shfl_xor(sm, m, 32);
      ph[h * 64 + j0] = e0;
      ph[h * 64 + j0 + 32] = e1;
      __syncthreads();
      float o = 0.f;
      for (int j = 0; j <= t; ++j) o += ph[h * 64 + j] * Vlds[j * 256 + tid];
      ol[tid] = o / sm;
      __syncthreads();
      float acc = sa_out_b[myl * 256 + tid];
      const float4* w4 = reinterpret_cast<const float4*>(sa_out_w + (size_t)(myl * 256 + tid) * 256);
#pragma unroll 4
      for (int k = 0; k < 64; ++k) {
        float4 wv = w4[k];
        acc += wv.x * ol[4 * k] + wv.y * ol[4 * k + 1] + wv.z * ol[4 * k + 2] + wv.w * ol[4 * k + 3];
      }
      acc += xres;
      float y = block_ln256(acc, tid, red8, ln_g[(myl * 3 + 0) * 256 + tid],
                            ln_b[(myl * 3 + 0) * 256 + tid]);
      float y2 = block_ln256(y + caval, tid, red8,
                             ln_g[(myl * 3 + 1) * 256 + tid], ln_b[(myl * 3 + 1) * 256 + tid]);
      gst(u + myl * 2048 + myb * 256 + tid, y2);
      bump(FL + FU(myl) * FSTR);

      if (myl == 0) {
        // xf: final LN after layer-3 FFN
        unsigned s3 = waitf(FL + FFPX(3, bid & 7) * FSTR, 8u * (unsigned)(t + 1), &saltsh);
        float uv; float4 f0, f1;
        pull1_2q(&uv, &f0, &f1, u + 3 * 2048 + myb * 256 + tid,
                 ffp + 1 * 16384 + (myb * 256 + tid) * 8, s3);  // par(l=3)=1
        float a = uv + ff2_b[3 * 256 + tid]
                + f0.x + f0.y + f0.z + f0.w + f1.x + f1.y + f1.z + f1.w;
        float xfv = block_ln256(a, tid, red8, ln_g[(3 * 3 + 2) * 256 + tid],
                                ln_b[(3 * 3 + 2) * 256 + tid]);
        gst(xf + myb * 256 + tid, xfv);
        bump8(FL + FXF(0) * FSTR);
      }
      unsigned s4 = waitf(FL + FXF(bid & 7) * FSTR, 8u * (unsigned)(t + 1), &saltsh);
      fc_phase(bid, tid, t, s4, xf, fc_w, fc_b, out, pv, pi, xl, rv, ri);
      bump(FL + FFC(bid & 7) * FSTR);
    }
  } else if (bid < 56) {
    // ======= QKV role: 32 rows of 768; redundant x-compute (argmax/LN) =======
    int qi = bid - 32;
    for (int t = 0; t < NSTEP; ++t) {
      for (int l = 0; l < 4; ++l) {
        if (l == 0) {
          if (t == 0) {
            if (tid < 8) toks[tid] = BOSTOK;
            __syncthreads();
          } else {
            unsigned s = wait_fcsum(FL, 256u * (unsigned)t, &saltsh);
            int i0 = tid >> 3, b = tid & 7;
            float pvv[8], piv[8];
            pull8p(pvv, pv + (i0 + 0) * 8 + b, pv + (i0 + 32) * 8 + b, pv + (i0 + 64) * 8 + b,
                   pv + (i0 + 96) * 8 + b, pv + (i0 + 128) * 8 + b, pv + (i0 + 160) * 8 + b,
                   pv + (i0 + 192) * 8 + b, pv + (i0 + 224) * 8 + b, s);
            const float* pif = (const float*)pi;
            pull8p(piv, pif + (i0 + 0) * 8 + b, pif + (i0 + 32) * 8 + b, pif + (i0 + 64) * 8 + b,
                   pif + (i0 + 96) * 8 + b, pif + (i0 + 128) * 8 + b, pif + (i0 + 160) * 8 + b,
                   pif + (i0 + 192) * 8 + b, pif + (i0 + 224) * 8 + b, s);
            float bv = -3e38f; int bi = 2147483647;
#pragma unroll
            for (int k = 0; k < 8; ++k) {
              float v = pvv[k]; int id = __float_as_int(piv[k]);
              if (v > bv || (v == bv && id < bi)) { bv = v; bi = id; }
            }
            rv[tid] = bv; ri[tid] = bi;
            __syncthreads();
            for (int off = 128; off >= 8; off >>= 1) {
              if (tid < off) {
                float v = rv[tid + off]; int id = ri[tid + off];
                if (v > rv[tid] || (v == rv[tid] && id < ri[tid])) { rv[tid] = v; ri[tid] = id; }
              }
              __syncthreads();
            }
            if (tid < 8) toks[tid] = ri[tid];
            __syncthreads();
          }
          for (int b = 0; b < 8; ++b)
            xl[b * 260 + tid] = tok_emb[(size_t)toks[b] * 256 + tid] + pos_enc[t * 256 + tid];
          __syncthreads();
        } else {
          unsigned s = waitf(FL + FFPX(l - 1, bid & 7) * FSTR, 8u * (unsigned)(t + 1), &saltsh);
          int lp = l - 1, par = lp & 1;
          float u8[8];
          pull8p(u8, u + lp * 2048 + 0 * 256 + tid, u + lp * 2048 + 1 * 256 + tid,
                 u + lp * 2048 + 2 * 256 + tid, u + lp * 2048 + 3 * 256 + tid,
                 u + lp * 2048 + 4 * 256 + tid, u + lp * 2048 + 5 * 256 + tid,
                 u + lp * 2048 + 6 * 256 + tid, u + lp * 2048 + 7 * 256 + tid, s);
          float4 fA[8], fB[8];
          const float* fb = ffp + par * 16384;
          pull4x8(fA, fb + (0 * 256 + tid) * 8, fb + (1 * 256 + tid) * 8,
                  fb + (2 * 256 + tid) * 8, fb + (3 * 256 + tid) * 8, s);
          pull4x8(fB, fb + (4 * 256 + tid) * 8, fb + (5 * 256 + tid) * 8,
                  fb + (6 * 256 + tid) * 8, fb + (7 * 256 + tid) * 8, s);
          float g = ln_g[(lp * 3 + 2) * 256 + tid], bt = ln_b[(lp * 3 + 2) * 256 + tid];
          float f2b = ff2_b[lp * 256 + tid];
#pragma unroll
          for (int b = 0; b < 8; ++b) {
            float4 q0 = (b < 4) ? fA[2 * b] : fB[2 * (b - 4)];
            float4 q1 = (b < 4) ? fA[2 * b + 1] : fB[2 * (b - 4) + 1];
            float a = u8[b] + f2b + q0.x + q0.y + q0.z + q0.w + q1.x + q1.y + q1.z + q1.w;
            xl[b * 260 + tid] = block_ln256(a, tid, red8, g, bt);
          }
          __syncthreads();
        }
        // GEMV rows qi*32..+32
        int r = tid >> 3, b8 = tid & 7;
        int row = qi * 32 + r;
        float acc = sa_in_b[l * 768 + row];
        const float4* w4 = reinterpret_cast<const float4*>(sa_in_w + (size_t)(l * 768 + row) * 256);
        const float4* xv = reinterpret_cast<const float4*>(xl + b8 * 260);
#pragma unroll 8
        for (int k = 0; k < 64; ++k) {
          float4 wv = w4[k]; float4 xq = xv[k];
          acc += wv.x * xq.x + wv.y * xq.y + wv.z * xq.z + wv.w * xq.w;
        }
        if (row < 256) gst(qb + b8 * 256 + row, acc);
        else if (row < 512) gst(kb + b8 * 256 + (row - 256), acc);
        else gst(vb + b8 * 256 + (row - 512), acc);
        bump(FL + FQKV(l) * FSTR);
      }
      unsigned s4 = waitf(FL + FXF(bid & 7) * FSTR, 8u * (unsigned)(t + 1), &saltsh);
      fc_phase(bid, tid, t, s4, xf, fc_w, fc_b, out, pv, pi, xl, rv, ri);
      bump(FL + FFC(bid & 7) * FSTR);
    }
  } else if (bid < 64) {
    // ======= FFN role: slice s (256 neurons), transposed partial store =======
    int s = bid - 56;
    for (int t = 0; t < NSTEP; ++t) {
      for (int l = 0; l < 4; ++l) {
        unsigned sv = waitf(FL + FU(l) * FSTR, 8u * (unsigned)(t + 1), &saltsh);
        {
          float u8[8];
          pull8p(u8, u + l * 2048 + 0 * 256 + tid, u + l * 2048 + 1 * 256 + tid,
                 u + l * 2048 + 2 * 256 + tid, u + l * 2048 + 3 * 256 + tid,
                 u + l * 2048 + 4 * 256 + tid, u + l * 2048 + 5 * 256 + tid,
                 u + l * 2048 + 6 * 256 + tid, u + l * 2048 + 7 * 256 + tid, sv);
#pragma unroll
          for (int b = 0; b < 8; ++b) xl[b * 260 + tid] = u8[b];
        }
        __syncthreads();
        // ff1: neuron row s*256+tid for all 8 batches
        {
          int row = s * 256 + tid;
          float acc[8];
          float bb = ff1_b[l * 2048 + row];
#pragma unroll
          for (int b = 0; b < 8; ++b) acc[b] = bb;
          const float4* w4 = reinterpret_cast<const float4*>(ff1_w + (size_t)(l * 2048 + row) * 256);
          for (int k = 0; k < 64; ++k) {
            float4 wv = w4[k];
#pragma unroll
            for (int b = 0; b < 8; ++b) {
              const float4 xq = reinterpret_cast<const float4*>(xl + b * 260)[k];
              acc[b] += wv.x * xq.x + wv.y * xq.y + wv.z * xq.z + wv.w * xq.w;
            }
          }
#pragma unroll
          for (int b = 0; b < 8; ++b) h1l[tid * 9 + b] = fmaxf(acc[b], 0.f);
        }
        __syncthreads();
        // ff2 partial: out-dim tid, neurons s*256..+256
        {
          float facc[8] = {0, 0, 0, 0, 0, 0, 0, 0};
          const float* w2p = ff2_w + (size_t)(l * 256 + tid) * 2048 + s * 256;
          for (int n = 0; n < 256; ++n) {
            float wv = w2p[n];
#pragma unroll
            for (int b = 0; b < 8; ++b) facc[b] += wv * h1l[n * 9 + b];
          }
          int par = l & 1;
#pragma unroll
          for (int b = 0; b < 8; ++b)
            gst(ffp + par * 16384 + (b * 256 + tid) * 8 + s, facc[b]);
        }
        bump8(FL + FFPX(l, 0) * FSTR);
        __syncthreads();
      }
      unsigned s4 = waitf(FL + FXF(bid & 7) * FSTR, 8u * (unsigned)(t + 1), &saltsh);
      fc_phase(bid, tid, t, s4, xf, fc_w, fc_b, out, pv, pi, xl, rv, ri);
      bump(FL + FFC(bid & 7) * FSTR);
    }
  } else {
    // ======= fc-only role =======
    for (int t = 0; t < NSTEP; ++t) {
      unsigned s4 = waitf(FL + FXF(bid & 7) * FSTR, 8u * (unsigned)(t + 1), &saltsh);
      fc_phase(bid, tid, t, s4, xf, fc_w, fc_b, out, pv, pi, xl, rv, ri);
      bump(FL + FFC(bid & 7) * FSTR);
    }
  }
}

extern "C" void kernel_launch(void* const* d_in, const int* in_sizes, int n_in,
                              void* d_out, int out_size, void* d_ws, size_t ws_size,
                              hipStream_t stream) {
  (void)in_sizes; (void)n_in; (void)out_size; (void)ws_size;
  const float* embedding = (const float*)d_in[0];
  const float* w_proj   = (const float*)d_in[1];
  const float* b_proj   = (const float*)d_in[2];
  const float* tok_emb  = (const float*)d_in[3];
  const float* pos_enc  = (const float*)d_in[4];
  const float* sa_in_w  = (const float*)d_in[5];
  const float* sa_in_b  = (const float*)d_in[6];
  const float* sa_out_w = (const float*)d_in[7];
  const float* sa_out_b = (const float*)d_in[8];
  const float* ca_in_w  = (const float*)d_in[9];
  const float* ca_in_b  = (const float*)d_in[10];
  const float* ca_out_w = (const float*)d_in[11];
  const float* ca_out_b = (const float*)d_in[12];
  const float* ff1_w    = (const float*)d_in[13];
  const float* ff1_b    = (const float*)d_in[14];
  const float* ff2_w    = (const float*)d_in[15];
  const float* ff2_b    = (const float*)d_in[16];
  const float* ln_g     = (const float*)d_in[17];
  const float* ln_b     = (const float*)d_in[18];
  const float* fc_w     = (const float*)d_in[19];
  const float* fc_b     = (const float*)d_in[20];
  float* out = (float*)d_out;
  float* wsf = (float*)d_ws;
  int*   wsi = (int*)d_ws;

  // Allow 104KB dynamic LDS (host-side attribute set; capture-safe).
  (void)hipFuncSetAttribute(reinterpret_cast<const void*>(k_flow4),
                            hipFuncAttributeMaxDynamicSharedMemorySize, DYN_LDS_BYTES);
  // Zero flag lines each call (captured into the graph; deterministic replays).
  (void)hipMemsetAsync(d_ws, 0, 16384, stream);
  // NORMAL launch (graph-capturable). 256 blocks / 256 CUs at 1 block/CU => co-resident;
  // the flag protocol needs co-residency only, not cooperative-launch semantics.
  hipLaunchKernelGGL(k_flow4, dim3(NBLK), dim3(256), DYN_LDS_BYTES, stream,
                     embedding, w_proj, b_proj, tok_emb, pos_enc,
                     sa_in_w, sa_in_b, sa_out_w, sa_out_b,
                     ca_in_w, ca_in_b, ca_out_w, ca_out_b,
                     ff1_w, ff1_b, ff2_w, ff2_b,
                     ln_g, ln_b, fc_w, fc_b,
                     out, wsf, wsi);
}